// Round 13
// baseline (847.906 us; speedup 1.0000x reference)
//
#include <hip/hip_runtime.h>
#include <hip/hip_bf16.h>
#include <cstddef>

// ---------------- problem constants ----------------
constexpr int cN_LOW  = 20000;
constexpr int cN_HIGH = 150000;
constexpr int cSEQ = 25;
constexpr int cHIN = 25;
constexpr int cHHID = 25;
constexpr int cENC = 32;
constexpr int cHIGH_IN = 7;
constexpr int cD = 16;
constexpr int cNL = 5;
constexpr int cE_L2H = 1350000;
constexpr int cE_HH = 1200000;
constexpr float cEPS = 1e-5f;
constexpr float cSLOPE = 0.2f;
constexpr float INV_NLOW  = 1.0f / (float)cN_LOW;
constexpr float INV_NHIGH = 1.0f / (float)cN_HIGH;

constexpr int cHSP = 640;     // padded hs row stride: 10 exact 64-f chunks

// XCD sharding (r3: confirmed win)
constexpr int cNSH = 8;
constexpr int cSH_RANGE = cN_HIGH / cNSH;          // 18750
static_assert(cN_HIGH % cNSH == 0, "shard ranges must be exact");

// scan geometry
constexpr int SC_ELEM = 1024;
constexpr int SC_NB   = (cN_HIGH + SC_ELEM - 1) / SC_ELEM;     // 147
static_assert(SC_NB <= 256, "top scan assumes <=256 partials");

// r13: radix-partition CSR build. r11/r12 diagnosis: 8x-replicated grid
// streams the full 20.4MB edge data per pass (fetch 80MB) and the streams
// evict dirty out-lines (WRITE 104-112MB for 10.2MB payload); nt-loads
// didn't help. Now: one multi-split pass into per-shard (src,dst) buckets,
// then hist/scatter read ONLY their XCD's ~3.6MB bucket (L2-resident).
constexpr int cEPB  = 2048;                               // edges per part block
constexpr int cPT_A = (cE_HH  + cEPB - 1) / cEPB;         // 586
constexpr int cPT_B = (cE_L2H + cEPB - 1) / cEPB;         // 660
constexpr int cREG_A = cE_HH  / cNSH + 65536;             // 215536 pairs/shard
constexpr int cREG_B = cE_L2H / cNSH + 65536;             // 234286 pairs/shard
constexpr int cHB_A = (cREG_A + 255) / 256;               // 842 blocks/shard
constexpr int cHB_B = (cREG_B + 255) / 256;               // 916

// ---------------- workspace layout (4-byte element offsets) ----------------
constexpr size_t OFF_HS   = 0;                                   // [N_LOW*640]
constexpr size_t SZ_HS    = (size_t)cN_LOW * cHSP;
constexpr size_t OFF_AGG  = 0;                                   // alias (hs dead after k_dense)
constexpr size_t OFF_ENC  = OFF_HS + SZ_HS;                      // [N_LOW*32]
constexpr size_t SZ_ENC   = (size_t)cN_LOW * cENC;
constexpr size_t OFF_XA   = OFF_ENC + SZ_ENC;
constexpr size_t OFF_XB   = OFF_XA + (size_t)cN_HIGH * cD;
constexpr size_t OFF_XL   = OFF_XB + (size_t)cN_HIGH * cD;       // selfq [N_HIGH]
constexpr size_t OFF_XR   = OFF_XL + (size_t)cN_HIGH * cD;
constexpr size_t OFF_STAT = OFF_XR + (size_t)cN_HIGH * cD;       // [256]
constexpr size_t OFF_RPH  = OFF_STAT + 256;                      // rowptr_hh [N_HIGH+4]
constexpr size_t OFF_SRH  = OFF_RPH + cN_HIGH + 4;               // src_hh [E_HH]
constexpr size_t OFF_RPL  = OFF_SRH + cE_HH;                     // rowptr_l2h [N_HIGH+4]
constexpr size_t OFF_SRL  = OFF_RPL + cN_HIGH + 4;               // src_l2h [E_L2H]
constexpr size_t OFF_CUR  = OFF_SRL + cE_L2H;                    // cursor [N_HIGH] (hh)
constexpr size_t OFF_PART = OFF_CUR + cN_HIGH;                   // partials [256] (hh)
constexpr size_t OFF_XLB  = OFF_PART + 256;                      // xl bf16 [N_HIGH*16 ushort]
// overlays in the hs region (dead until k_gru, which launches after scatter)
constexpr size_t OFF_CUR2 = OFF_HS;                              // cursor2 [N_HIGH]
constexpr size_t OFF_PART2= OFF_HS + cN_HIGH + 16;               // partials2 [256]
constexpr size_t OFF_SCUR = OFF_PART2 + 256 + 16;                // shardCur [16]
constexpr size_t OFF_PAIRA= OFF_SCUR + 32;                       // int2[8*cREG_A]
constexpr size_t OFF_PAIRB= OFF_PAIRA + (size_t)2 * 8 * cREG_A;  // int2[8*cREG_B]
static_assert(OFF_PAIRB + (size_t)2 * 8 * cREG_B < SZ_HS, "pair buckets fit in hs");

typedef _Float16 half_t;
typedef half_t half2_t __attribute__((ext_vector_type(2)));

__device__ __forceinline__ float fast_sigmoid(float a) {
  return __builtin_amdgcn_rcpf(1.0f + __expf(-a));
}
__device__ __forceinline__ float fast_tanh(float a) {
  float t = __expf(-2.0f * a);
  return (1.0f - t) * __builtin_amdgcn_rcpf(1.0f + t);
}
__device__ __forceinline__ unsigned int f32_to_bf16_bits(float f) {
  unsigned int u = __float_as_uint(f);
  return (u + 0x7FFFu + ((u >> 16) & 1u)) >> 16;     // RNE
}
__device__ __forceinline__ void unpack8(uint4 v, float* x) {
  const unsigned int* w = (const unsigned int*)&v;
  #pragma unroll
  for (int m = 0; m < 4; ++m) {
    x[2 * m]     = __uint_as_float(w[m] << 16);
    x[2 * m + 1] = __uint_as_float(w[m] & 0xFFFF0000u);
  }
}

// ---------------- GRU kernel v8b (FROZEN: structural floor ~89us) ---------
constexpr int GW2 = 4;                // waves per block; 2 nodes/wave -> 8/block

__global__ __launch_bounds__(256, 4)
void k_gru(const float* __restrict__ x_low,
           const float* __restrict__ Wih, const float* __restrict__ Whh,
           const float* __restrict__ bih, const float* __restrict__ bhh,
           float* __restrict__ hs) {
  __shared__ __align__(16) half_t  sx   [GW2][2][25][32];   // x, then gi2 (12.8 KB)
  __shared__ __align__(16) half2_t sgi01[GW2][2][25][32];   // (gi0,gi1)   (25.6 KB)
  __shared__ __align__(16) half_t  sh   [GW2][2][2][32];    // h dbuf      ( 1.0 KB)

  int tid  = threadIdx.x;
  int wv   = tid >> 6;
  int lane = tid & 63;
  int hf   = lane >> 5;          // node half 0/1
  int j    = lane & 31;          // 0..31; active if < 25
  bool act = j < 25;
  int nw   = blockIdx.x * GW2 + wv;       // wave's node pair index
  int n    = nw * 2 + hf;                 // this half's node

  // ---- stage x (2 nodes, 1250 contiguous floats) into LDS as half ----
  {
    const float* xb = x_low + (size_t)nw * 1250;
    for (int i = lane; i < 1250; i += 64) {
      float v = xb[i];
      int node = i / 625;
      int rem  = i - node * 625;
      int t    = rem / 25;
      int k    = rem - t * 25;
      sx[wv][node][t][k] = (half_t)v;
    }
  }
  // zero pads (k=25..31) of sx and sh so b128 reads never see garbage
  if (!act) {
    #pragma unroll
    for (int t = 0; t < cSEQ; ++t) sx[wv][hf][t][j] = (half_t)0.0f;
    sh[wv][hf][0][j] = (half_t)0.0f;
    sh[wv][hf][1][j] = (half_t)0.0f;
  } else {
    sh[wv][hf][0][j] = (half_t)0.0f;     // h0 = 0
  }

  // ---- weight regs: first Wih (prologue), then Whh (loop) ----
  half2_t w0[13], w1[13], w2[13];
  float b0 = 0.0f, b1 = 0.0f, b2 = 0.0f;
  if (act) {
    #pragma unroll
    for (int k = 0; k < 13; ++k) {
      int i0 = 2 * k, i1 = 2 * k + 1;
      float a0 = Wih[j * 25 + i0];
      float a1 = (i1 < 25) ? Wih[j * 25 + i1] : 0.0f;
      float c0 = Wih[(25 + j) * 25 + i0];
      float c1 = (i1 < 25) ? Wih[(25 + j) * 25 + i1] : 0.0f;
      float d0 = Wih[(50 + j) * 25 + i0];
      float d1 = (i1 < 25) ? Wih[(50 + j) * 25 + i1] : 0.0f;
      w0[k] = half2_t{(half_t)a0, (half_t)a1};
      w1[k] = half2_t{(half_t)c0, (half_t)c1};
      w2[k] = half2_t{(half_t)d0, (half_t)d1};
    }
    b0 = bih[j]; b1 = bih[25 + j]; b2 = bih[50 + j];
  } else {
    #pragma unroll
    for (int k = 0; k < 13; ++k) { w0[k] = half2_t{(half_t)0.0f, (half_t)0.0f};
      w1[k] = w0[k]; w2[k] = w0[k]; }
  }

  // ---- prologue: gi[t] for all t; gi0/gi1 -> sgi01, gi2 -> sx[t] (overlay)
  for (int t = 0; t < cSEQ; ++t) {
    uint4 r0 = *(const uint4*)&sx[wv][hf][t][0];
    uint4 r1 = *(const uint4*)&sx[wv][hf][t][8];
    uint4 r2 = *(const uint4*)&sx[wv][hf][t][16];
    uint4 r3 = *(const uint4*)&sx[wv][hf][t][24];
    uint4 rr[4] = {r0, r1, r2, r3};
    const half2_t* vp = (const half2_t*)rr;
    float g0 = b0, g1 = b1, g2 = b2;
    #pragma unroll
    for (int k = 0; k < 13; ++k) {
      half2_t v = vp[k];
      g0 = __builtin_amdgcn_fdot2(w0[k], v, g0, false);
      g1 = __builtin_amdgcn_fdot2(w1[k], v, g1, false);
      g2 = __builtin_amdgcn_fdot2(w2[k], v, g2, false);
    }
    if (act) {
      sgi01[wv][hf][t][j] = half2_t{(half_t)g0, (half_t)g1};
      sx[wv][hf][t][j] = (half_t)g2;      // overlay: sx[t] row dead after reads above
    }
  }

  // ---- swap weights to Whh / bhh ----
  if (act) {
    #pragma unroll
    for (int k = 0; k < 13; ++k) {
      int i0 = 2 * k, i1 = 2 * k + 1;
      float a0 = Whh[j * 25 + i0];
      float a1 = (i1 < 25) ? Whh[j * 25 + i1] : 0.0f;
      float c0 = Whh[(25 + j) * 25 + i0];
      float c1 = (i1 < 25) ? Whh[(25 + j) * 25 + i1] : 0.0f;
      float d0 = Whh[(50 + j) * 25 + i0];
      float d1 = (i1 < 25) ? Whh[(50 + j) * 25 + i1] : 0.0f;
      w0[k] = half2_t{(half_t)a0, (half_t)a1};
      w1[k] = half2_t{(half_t)c0, (half_t)c1};
      w2[k] = half2_t{(half_t)d0, (half_t)d1};
    }
    b0 = bhh[j]; b1 = bhh[25 + j]; b2 = bhh[50 + j];
  }

  float* hrow = hs + (size_t)n * cHSP;
  if (j < 15) hrow[625 + j] = 0.0f;      // zero hs pad for dense chunks

  // ---- serial loop: h-side only, 2 nodes/wave ----
  float hprev = 0.0f;
  int p = 0;
  for (int t = 0; t < cSEQ; ++t) {
    uint4 r0 = *(const uint4*)&sh[wv][hf][p][0];
    uint4 r1 = *(const uint4*)&sh[wv][hf][p][8];
    uint4 r2 = *(const uint4*)&sh[wv][hf][p][16];
    uint4 r3 = *(const uint4*)&sh[wv][hf][p][24];
    uint4 rr[4] = {r0, r1, r2, r3};
    const half2_t* vp = (const half2_t*)rr;
    float g0 = b0, g1 = b1, g2 = b2;
    #pragma unroll
    for (int k = 0; k < 13; ++k) {
      half2_t v = vp[k];
      g0 = __builtin_amdgcn_fdot2(w0[k], v, g0, false);
      g1 = __builtin_amdgcn_fdot2(w1[k], v, g1, false);
      g2 = __builtin_amdgcn_fdot2(w2[k], v, g2, false);
    }
    if (act) {
      half2_t gv = sgi01[wv][hf][t][j];
      float gi0 = (float)gv.x;
      float gi1 = (float)gv.y;
      float gi2 = (float)sx[wv][hf][t][j];   // gi2 overlay
      float r  = fast_sigmoid(gi0 + g0);
      float z  = fast_sigmoid(gi1 + g1);
      float nn = fast_tanh(gi2 + r * g2);
      float hnew = (1.0f - z) * nn + z * hprev;
      hprev = hnew;
      sh[wv][hf][p ^ 1][j] = (half_t)hnew;
      hrow[t * 25 + j] = hnew;
    }
    p ^= 1;
  }
}

// ---------------- dense 625->32 + relu + BN stats (v4) ----------------
constexpr int cDN = 32;      // nodes per block
__global__ __launch_bounds__(256)
void k_dense(const float* __restrict__ hs, const float* __restrict__ W,
             const float* __restrict__ b, float* __restrict__ enc,
             float* __restrict__ statsEnc) {
  __shared__ __align__(16) float sW2[640 * 32];        // 80 KB: [f][e2-pair]
  __shared__ __align__(16) float sH[2][cDN * 68];      // 17.4 KB
  __shared__ float sstat[2 * cENC];
  int tid = threadIdx.x;
  for (int i = tid; i < 32 * 625; i += 256) {
    int e = i / 625, f = i % 625;
    sW2[f * 32 + (e & 15) * 2 + (e >> 4)] = W[i];
  }
  for (int i = tid; i < 32 * 15; i += 256)
    sW2[(625 + (i >> 5)) * 32 + (i & 31)] = 0.0f;
  if (tid < 2 * cENC) sstat[tid] = 0.0f;

  int e2 = tid & 15;
  int ng = (tid >> 4) & 3;
  int w  = tid >> 6;
  int rA = 8 * w + 2 * ng;
  int rB = rA + 1;
  size_t nbase = (size_t)blockIdx.x * cDN;

  int srow = tid >> 4;
  int sf4  = (tid & 15) * 4;
  const float* hsb = hs + nbase * cHSP;
  {
    float4 v0 = *(const float4*)(hsb + (size_t)srow * cHSP + sf4);
    float4 v1 = *(const float4*)(hsb + (size_t)(srow + 16) * cHSP + sf4);
    *(float4*)&sH[0][srow * 68 + sf4] = v0;
    *(float4*)&sH[0][(srow + 16) * 68 + sf4] = v1;
  }
  __syncthreads();

  float a00 = 0.0f, a01 = 0.0f, a10 = 0.0f, a11 = 0.0f;
  for (int c = 0; c < 10; ++c) {
    int buf = c & 1;
    if (c + 1 < 10) {
      const float* src = hsb + (c + 1) * 64;
      float4 v0 = *(const float4*)(src + (size_t)srow * cHSP + sf4);
      float4 v1 = *(const float4*)(src + (size_t)(srow + 16) * cHSP + sf4);
      *(float4*)&sH[buf ^ 1][srow * 68 + sf4] = v0;
      *(float4*)&sH[buf ^ 1][(srow + 16) * 68 + sf4] = v1;
    }
    const float* WC = sW2 + c * 64 * 32;
    #pragma unroll
    for (int fg = 0; fg < 16; ++fg) {
      float4 hA = *(const float4*)&sH[buf][rA * 68 + fg * 4];
      float4 hB = *(const float4*)&sH[buf][rB * 68 + fg * 4];
      const float* ha = (const float*)&hA;
      const float* hb = (const float*)&hB;
      #pragma unroll
      for (int k = 0; k < 4; ++k) {
        float2 wv = *(const float2*)&WC[(fg * 4 + k) * 32 + e2 * 2];
        a00 += wv.x * ha[k]; a01 += wv.y * ha[k];
        a10 += wv.x * hb[k]; a11 += wv.y * hb[k];
      }
    }
    __syncthreads();
  }
  float blo = b[e2], bhi = b[e2 + 16];
  float v00 = fmaxf(a00 + blo, 0.0f);
  float v01 = fmaxf(a01 + bhi, 0.0f);
  float v10 = fmaxf(a10 + blo, 0.0f);
  float v11 = fmaxf(a11 + bhi, 0.0f);
  size_t nA = nbase + rA, nB = nbase + rB;
  enc[nA * cENC + e2]      = v00;
  enc[nA * cENC + e2 + 16] = v01;
  enc[nB * cENC + e2]      = v10;
  enc[nB * cENC + e2 + 16] = v11;

  float s1lo = v00 + v10, s1hi = v01 + v11;
  float s2lo = v00 * v00 + v10 * v10, s2hi = v01 * v01 + v11 * v11;
  s1lo += __shfl_xor(s1lo, 16); s1hi += __shfl_xor(s1hi, 16);
  s2lo += __shfl_xor(s2lo, 16); s2hi += __shfl_xor(s2hi, 16);
  s1lo += __shfl_xor(s1lo, 32); s1hi += __shfl_xor(s1hi, 32);
  s2lo += __shfl_xor(s2lo, 32); s2hi += __shfl_xor(s2hi, 32);
  if ((tid & 63) < 16) {
    atomicAdd(&sstat[e2], s1lo);
    atomicAdd(&sstat[e2 + 16], s1hi);
    atomicAdd(&sstat[cENC + e2], s2lo);
    atomicAdd(&sstat[cENC + e2 + 16], s2hi);
  }
  __syncthreads();
  if (tid < 2 * cENC) atomicAdd(&statsEnc[tid], sstat[tid]);
}

// ---------------- radix-partition CSR build (r13) ----------------
__global__ void k_initsc(int* __restrict__ scur) {
  int t = threadIdx.x;
  if (t < 8) scur[t] = t * cREG_A;
  else if (t < 16) scur[t] = (t - 8) * cREG_B;
}

// multi-split: 2048 edges/block -> per-shard buckets (absolute idx in pair buf)
__global__ __launch_bounds__(256)
void k_part(const int* __restrict__ srcA, const int* __restrict__ dstA,
            const int* __restrict__ srcB, const int* __restrict__ dstB,
            int* __restrict__ scur, int2* __restrict__ pairA, int2* __restrict__ pairB) {
  __shared__ int cnt[8];
  __shared__ int base[8];
  int bid = blockIdx.x;
  const int* src; const int* dst; int nE; int2* pair; int* sc;
  if (bid < cPT_A) { src = srcA; dst = dstA; nE = cE_HH; pair = pairA; sc = scur; }
  else { bid -= cPT_A; src = srcB; dst = dstB; nE = cE_L2H; pair = pairB; sc = scur + 8; }
  int tid = threadIdx.x;
  if (tid < 8) cnt[tid] = 0;
  __syncthreads();
  int e0 = bid * cEPB;
  int myd[8], mys[8], mysh[8];
  #pragma unroll
  for (int k = 0; k < 8; ++k) {
    int e = e0 + k * 256 + tid;
    if (e < nE) {
      int d = __builtin_nontemporal_load(dst + e);
      int s = __builtin_nontemporal_load(src + e);
      myd[k] = d; mys[k] = s;
      int sh = d / cSH_RANGE;
      mysh[k] = sh;
      atomicAdd(&cnt[sh], 1);
    } else mysh[k] = -1;
  }
  __syncthreads();
  if (tid < 8) base[tid] = atomicAdd(&sc[tid], cnt[tid]);
  __syncthreads();
  if (tid < 8) cnt[tid] = 0;          // reuse as rank cursors
  __syncthreads();
  #pragma unroll
  for (int k = 0; k < 8; ++k) {
    if (mysh[k] >= 0) {
      int r = atomicAdd(&cnt[mysh[k]], 1);
      pair[base[mysh[k]] + r] = make_int2(mys[k], myd[k]);
    }
  }
}

// hist over buckets: shard = bid&7 (XCD-affine); reads ONLY its bucket
__global__ void k_hist2b(const int2* __restrict__ pairA, int* __restrict__ cntA,
                         const int2* __restrict__ pairB, int* __restrict__ cntB,
                         const int* __restrict__ scur) {
  int bid = blockIdx.x;
  const int2* pair; int* cnt; const int* sce; int reg;
  if (bid < 8 * cHB_A) { pair = pairA; cnt = cntA; sce = scur; reg = cREG_A; }
  else { bid -= 8 * cHB_A; pair = pairB; cnt = cntB; sce = scur + 8; reg = cREG_B; }
  int shard = bid & 7;
  int tile  = bid >> 3;
  int idx = shard * reg + tile * 256 + threadIdx.x;
  if (idx < sce[shard]) {
    int d = pair[idx].y;
    atomicAdd(&cnt[d], 1);
  }
}

__global__ void k_scatter2b(const int2* __restrict__ pairA, int* __restrict__ curA,
                            int* __restrict__ outA,
                            const int2* __restrict__ pairB, int* __restrict__ curB,
                            int* __restrict__ outB,
                            const int* __restrict__ scur) {
  int bid = blockIdx.x;
  const int2* pair; int* cur; int* out; const int* sce; int reg;
  if (bid < 8 * cHB_A) { pair = pairA; cur = curA; out = outA; sce = scur; reg = cREG_A; }
  else { bid -= 8 * cHB_A; pair = pairB; cur = curB; out = outB; sce = scur + 8; reg = cREG_B; }
  int shard = bid & 7;
  int tile  = bid >> 3;
  int idx = shard * reg + tile * 256 + threadIdx.x;
  if (idx < sce[shard]) {
    int2 p = pair[idx];
    int pos = atomicAdd(&cur[p.y], 1);
    out[pos] = p.x;
  }
}

__global__ void k_scan_local2(const int* __restrict__ degA, int* __restrict__ outA,
                              int* __restrict__ partA,
                              const int* __restrict__ degB, int* __restrict__ outB,
                              int* __restrict__ partB) {
  int bid = blockIdx.x;
  const int* deg; int* out; int* partial;
  if (bid < SC_NB) { deg = degA; out = outA; partial = partA; }
  else { bid -= SC_NB; deg = degB; out = outB; partial = partB; }
  const int n = cN_HIGH;
  int tid = threadIdx.x;
  int base = bid * SC_ELEM + tid * 4;
  int4 v = make_int4(0, 0, 0, 0);
  if (base + 3 < n) v = *(const int4*)(deg + base);
  else { int* pv = (int*)&v; for (int k = 0; k < 4; ++k) if (base + k < n) pv[k] = deg[base + k]; }
  int tsum = v.x + v.y + v.z + v.w;
  int lane = tid & 63;
  int inc = tsum;
  #pragma unroll
  for (int o = 1; o < 64; o <<= 1) { int t = __shfl_up(inc, o); if (lane >= o) inc += t; }
  __shared__ int wtot[4];
  if (lane == 63) wtot[tid >> 6] = inc;
  __syncthreads();
  int w = tid >> 6, wbase = 0;
  #pragma unroll
  for (int k = 0; k < 3; ++k) if (k < w) wbase += wtot[k];
  int ebase = wbase + inc - tsum;
  int4 o4;
  o4.x = ebase; o4.y = ebase + v.x; o4.z = o4.y + v.y; o4.w = o4.z + v.z;
  if (base + 3 < n) *(int4*)(out + base) = o4;
  else { int* po = (int*)&o4; for (int k = 0; k < 4; ++k) if (base + k < n) out[base + k] = po[k]; }
  if (tid == 255) partial[bid] = wbase + inc;
}

__global__ void k_scan_top2(int* __restrict__ partA, int* __restrict__ totalA,
                            int* __restrict__ partB, int* __restrict__ totalB) {
  int* partial = (blockIdx.x == 0) ? partA : partB;
  int* total_out = (blockIdx.x == 0) ? totalA : totalB;
  const int nb = SC_NB;
  __shared__ int sd[256];
  int tid = threadIdx.x;
  int v = (tid < nb) ? partial[tid] : 0;
  sd[tid] = v;
  __syncthreads();
  for (int off = 1; off < 256; off <<= 1) {
    int t = (tid >= off) ? sd[tid - off] : 0;
    __syncthreads();
    sd[tid] += t;
    __syncthreads();
  }
  if (tid < nb) partial[tid] = sd[tid] - v;
  if (tid == 255) *total_out = sd[255];
}

__global__ void k_scan_add2(int* __restrict__ rpA, const int* __restrict__ partA,
                            int* __restrict__ curA,
                            int* __restrict__ rpB, const int* __restrict__ partB,
                            int* __restrict__ curB) {
  int bid = blockIdx.x;
  int* rowptr; const int* partial; int* cursor;
  if (bid < SC_NB) { rowptr = rpA; partial = partA; cursor = curA; }
  else { bid -= SC_NB; rowptr = rpB; partial = partB; cursor = curB; }
  const int n = cN_HIGH;
  int base = bid * SC_ELEM + threadIdx.x * 4;
  int add = partial[bid];
  if (base + 3 < n) {
    int4 v = *(int4*)(rowptr + base);
    v.x += add; v.y += add; v.z += add; v.w += add;
    *(int4*)(rowptr + base) = v;
    *(int4*)(cursor + base) = v;
  } else {
    for (int k = 0; k < 4; ++k)
      if (base + k < n) { int t = rowptr[base + k] + add; rowptr[base + k] = t; cursor[base + k] = t; }
  }
}

// ---------------- l2h gather via CSR (2-way unrolled) ----------------
__global__ void k_gather_csr(const float* __restrict__ enc, const int* __restrict__ rowptr,
                             const int* __restrict__ srcs, const float* __restrict__ statsEnc,
                             const float* __restrict__ g, const float* __restrict__ bb,
                             float* __restrict__ agg) {
  __shared__ float ssc[cENC], ssh[cENC];
  int tid = threadIdx.x;
  if (tid < cENC) {
    float m = statsEnc[tid] * INV_NLOW;
    float var = statsEnc[cENC + tid] * INV_NLOW - m * m;
    float sc = g[tid] * rsqrtf(var + cEPS);
    ssc[tid] = sc;
    ssh[tid] = bb[tid] - m * sc;
  }
  __syncthreads();
  int c = tid & 31;
  int n = blockIdx.x * 8 + (tid >> 5);
  int lo = rowptr[n], hi = rowptr[n + 1];
  float sum = 0.0f;
  int i = lo;
  for (; i + 1 < hi; i += 2) {
    int s0 = srcs[i], s1 = srcs[i + 1];
    sum += enc[(size_t)s0 * cENC + c] + enc[(size_t)s1 * cENC + c];
  }
  if (i < hi) sum += enc[(size_t)srcs[i] * cENC + c];
  float deg = (float)(hi - lo);
  agg[(size_t)n * cENC + c] = (ssc[c] * sum + deg * ssh[c]) / fmaxf(deg, 1.0f);
}

// ---------------- down-projection + BN0 stats ----------------
__global__ void k_down(const float* __restrict__ agg,
                       const float* __restrict__ z_std, const float* __restrict__ land,
                       const float* __restrict__ Wrel, const float* __restrict__ brel,
                       const float* __restrict__ Wroot,
                       float* __restrict__ x0, float* __restrict__ stats) {
  __shared__ float sstat[2 * cD];
  __shared__ float sWrel[cD * cENC], sWroot[cD * cHIGH_IN], sbrel[cD];
  int tid = threadIdx.x;
  if (tid < 2 * cD) sstat[tid] = 0.0f;
  for (int i = tid; i < cD * cENC; i += 256) sWrel[i] = Wrel[i];
  if (tid < cD * cHIGH_IN) sWroot[tid] = Wroot[tid];
  if (tid < cD) sbrel[tid] = brel[tid];
  __syncthreads();

  int n = blockIdx.x * 256 + tid;
  bool valid = n < cN_HIGH;
  float a[cENC], zz[cHIGH_IN];
  if (valid) {
    const float4* ar4 = (const float4*)(agg + (size_t)n * cENC);
    #pragma unroll
    for (int k = 0; k < cENC / 4; ++k) {
      float4 t4 = ar4[k];
      a[4*k] = t4.x; a[4*k+1] = t4.y; a[4*k+2] = t4.z; a[4*k+3] = t4.w;
    }
    #pragma unroll
    for (int k = 0; k < 6; ++k) zz[k] = z_std[(size_t)n * 6 + k];
    zz[6] = land[n];
  } else {
    #pragma unroll
    for (int k = 0; k < cENC; ++k) a[k] = 0.0f;
    #pragma unroll
    for (int k = 0; k < cHIGH_IN; ++k) zz[k] = 0.0f;
  }
  int lane = tid & 63;
  #pragma unroll
  for (int d = 0; d < cD; ++d) {
    float acc = sbrel[d];
    #pragma unroll
    for (int k = 0; k < cENC; ++k) acc += a[k] * sWrel[d * cENC + k];
    #pragma unroll
    for (int k = 0; k < cHIGH_IN; ++k) acc += zz[k] * sWroot[d * cHIGH_IN + k];
    if (valid) x0[(size_t)n * cD + d] = acc;
    float v = valid ? acc : 0.0f;
    float s1 = v, s2 = v * v;
    #pragma unroll
    for (int o = 32; o > 0; o >>= 1) { s1 += __shfl_down(s1, o); s2 += __shfl_down(s2, o); }
    if (lane == 0) { atomicAdd(&sstat[d], s1); atomicAdd(&sstat[cD + d], s2); }
  }
  __syncthreads();
  if (tid < 2 * cD) atomicAdd(&stats[tid], sstat[tid]);
}

// ---------------- GAT node transform (emits xr, xlb bf16, self-logit) -----
__global__ void k_transform(const float* __restrict__ xin, const float* __restrict__ stats,
                            const float* __restrict__ g, const float* __restrict__ b,
                            const float* __restrict__ Wl, const float* __restrict__ bl,
                            const float* __restrict__ Wr, const float* __restrict__ br,
                            const float* __restrict__ att,
                            int applyRelu,
                            float* __restrict__ selfq, float* __restrict__ xr,
                            unsigned short* __restrict__ xlb) {
  __shared__ float ssc[cD], ssh[cD], sWl[cD * cD], sWr[cD * cD], sbl[cD], sbr[cD], satt[cD];
  int tid = threadIdx.x;
  if (tid < cD) {
    float m = stats[tid] * INV_NHIGH;
    float v = stats[cD + tid] * INV_NHIGH - m * m;
    float sc = g[tid] * rsqrtf(v + cEPS);
    ssc[tid] = sc;
    ssh[tid] = b[tid] - m * sc;
    sbl[tid] = bl[tid];
    sbr[tid] = br[tid];
    satt[tid] = att[tid];
  }
  if (tid < cD * cD) { sWl[tid] = Wl[tid]; sWr[tid] = Wr[tid]; }
  __syncthreads();

  int n = blockIdx.x * 256 + tid;
  if (n >= cN_HIGH) return;
  float act[cD];
  const float* xp = xin + (size_t)n * cD;
  #pragma unroll
  for (int d = 0; d < cD; ++d) {
    float v = xp[d] * ssc[d] + ssh[d];
    if (applyRelu) v = fmaxf(v, 0.0f);
    act[d] = v;
  }
  float alv[cD], arv[cD];
  float* xrp = xr + (size_t)n * cD;
  #pragma unroll
  for (int d = 0; d < cD; ++d) {
    float al = sbl[d], ar = sbr[d];
    #pragma unroll
    for (int k = 0; k < cD; ++k) { al += act[k] * sWl[d * cD + k]; ar += act[k] * sWr[d * cD + k]; }
    alv[d] = al;
    arv[d] = ar;
    xrp[d] = ar;
  }
  // self-loop attention logit
  float qq = 0.0f;
  #pragma unroll
  for (int d = 0; d < cD; ++d) {
    float u = alv[d] + arv[d];
    u = fmaxf(u, cSLOPE * u);
    qq += u * satt[d];
  }
  selfq[n] = qq;

  uint4 w0, w1;
  unsigned int* pw = (unsigned int*)&w0;
  #pragma unroll
  for (int k = 0; k < 4; ++k)
    pw[k] = f32_to_bf16_bits(alv[2 * k]) | (f32_to_bf16_bits(alv[2 * k + 1]) << 16);
  unsigned int* pw1 = (unsigned int*)&w1;
  #pragma unroll
  for (int k = 0; k < 4; ++k)
    pw1[k] = f32_to_bf16_bits(alv[8 + 2 * k]) | (f32_to_bf16_bits(alv[8 + 2 * k + 1]) << 16);
  uint4* dst = (uint4*)(xlb + (size_t)n * cD);
  dst[0] = w0;
  dst[1] = w1;
}

// ---------------- fused GAT edge pass v6: no xl array, 4-way gathers ------
template<int FINAL>
__global__ __launch_bounds__(256)
void k_edge(const float* __restrict__ selfq, const float* __restrict__ xr,
            const unsigned short* __restrict__ xlb,
            const int* __restrict__ rowptr, const int* __restrict__ srcs,
            const float* __restrict__ att, const float* __restrict__ bias,
            const float* __restrict__ pW, const float* __restrict__ pb,
            float* __restrict__ xout, float* __restrict__ stats,
            float* __restrict__ out) {
  __shared__ float sstat[2 * cD];
  int tid = threadIdx.x;
  if (!FINAL) {
    if (tid < 2 * cD) sstat[tid] = 0.0f;
    __syncthreads();
  }

  int half = tid & 1;
  int n = (blockIdx.x * 256 + tid) >> 1;
  bool valid = n < cN_HIGH;
  int base = half * 8;

  float av[8];
  #pragma unroll
  for (int k = 0; k < 8; ++k) av[k] = att[base + k];

  const uint4* xl4 = (const uint4*)xlb;
  float xrv[8], num[8];
  float denom = 1.0f;
  int lo = 0, hi = 0;
  if (valid) {
    #pragma unroll
    for (int k = 0; k < 2; ++k) {
      float4 t = *(const float4*)(xr + (size_t)n * cD + base + 4 * k);
      xrv[4*k] = t.x; xrv[4*k+1] = t.y; xrv[4*k+2] = t.z; xrv[4*k+3] = t.w;
    }
    // self contribution: own bf16 row + precomputed logit
    uint4 vs = xl4[(size_t)n * 2 + half];
    float xsv[8];
    unpack8(vs, xsv);
    float e = __expf(selfq[n]);
    denom = e;
    #pragma unroll
    for (int k = 0; k < 8; ++k) num[k] = e * xsv[k];
    lo = rowptr[n]; hi = rowptr[n + 1];
  } else {
    #pragma unroll
    for (int k = 0; k < 8; ++k) { num[k] = 0.0f; xrv[k] = 0.0f; }
  }

  int i = lo;
  for (; i + 3 < hi; i += 4) {
    int s0 = srcs[i], s1 = srcs[i + 1], s2 = srcs[i + 2], s3 = srcs[i + 3];
    uint4 v0 = xl4[(size_t)s0 * 2 + half];
    uint4 v1 = xl4[(size_t)s1 * 2 + half];
    uint4 v2 = xl4[(size_t)s2 * 2 + half];
    uint4 v3 = xl4[(size_t)s3 * 2 + half];
    float x0[8], x1[8], x2[8], x3[8];
    unpack8(v0, x0);
    unpack8(v1, x1);
    unpack8(v2, x2);
    unpack8(v3, x3);
    float q0 = 0.0f, q1 = 0.0f, q2 = 0.0f, q3 = 0.0f;
    #pragma unroll
    for (int k = 0; k < 8; ++k) {
      float u0 = x0[k] + xrv[k]; u0 = fmaxf(u0, cSLOPE * u0);
      float u1 = x1[k] + xrv[k]; u1 = fmaxf(u1, cSLOPE * u1);
      float u2 = x2[k] + xrv[k]; u2 = fmaxf(u2, cSLOPE * u2);
      float u3 = x3[k] + xrv[k]; u3 = fmaxf(u3, cSLOPE * u3);
      q0 += u0 * av[k]; q1 += u1 * av[k]; q2 += u2 * av[k]; q3 += u3 * av[k];
    }
    q0 += __shfl_xor(q0, 1);
    q1 += __shfl_xor(q1, 1);
    q2 += __shfl_xor(q2, 1);
    q3 += __shfl_xor(q3, 1);
    float e0 = __expf(q0), e1 = __expf(q1), e2 = __expf(q2), e3 = __expf(q3);
    denom += (e0 + e1) + (e2 + e3);
    #pragma unroll
    for (int k = 0; k < 8; ++k)
      num[k] += (e0 * x0[k] + e1 * x1[k]) + (e2 * x2[k] + e3 * x3[k]);
  }
  for (; i + 1 < hi; i += 2) {
    int s0 = srcs[i], s1 = srcs[i + 1];
    uint4 v0 = xl4[(size_t)s0 * 2 + half];
    uint4 v1 = xl4[(size_t)s1 * 2 + half];
    float x0[8], x1[8];
    unpack8(v0, x0);
    unpack8(v1, x1);
    float q0 = 0.0f, q1 = 0.0f;
    #pragma unroll
    for (int k = 0; k < 8; ++k) {
      float u0 = x0[k] + xrv[k]; u0 = fmaxf(u0, cSLOPE * u0);
      float u1 = x1[k] + xrv[k]; u1 = fmaxf(u1, cSLOPE * u1);
      q0 += u0 * av[k]; q1 += u1 * av[k];
    }
    q0 += __shfl_xor(q0, 1);
    q1 += __shfl_xor(q1, 1);
    float e0 = __expf(q0), e1 = __expf(q1);
    denom += e0 + e1;
    #pragma unroll
    for (int k = 0; k < 8; ++k) num[k] += e0 * x0[k] + e1 * x1[k];
  }
  if (i < hi) {
    int s = srcs[i];
    uint4 v = xl4[(size_t)s * 2 + half];
    float x[8];
    unpack8(v, x);
    float qq = 0.0f;
    #pragma unroll
    for (int k = 0; k < 8; ++k) {
      float u = x[k] + xrv[k]; u = fmaxf(u, cSLOPE * u);
      qq += u * av[k];
    }
    qq += __shfl_xor(qq, 1);
    float e = __expf(qq);
    denom += e;
    #pragma unroll
    for (int k = 0; k < 8; ++k) num[k] += e * x[k];
  }

  float cnt = (float)(hi - lo + 1);
  float inv = __builtin_amdgcn_rcpf(denom * cnt);
  float res[8];
  #pragma unroll
  for (int k = 0; k < 8; ++k)
    res[k] = valid ? (num[k] * inv + bias[base + k]) : 0.0f;

  if (FINAL) {
    float t = 0.0f;
    #pragma unroll
    for (int k = 0; k < 8; ++k) t += fmaxf(res[k], 0.0f) * pW[base + k];
    t += __shfl_xor(t, 1);
    if (valid && half == 0) out[n] = t + pb[0];
  } else {
    if (valid) {
      float4* op = (float4*)(xout + (size_t)n * cD + base);
      op[0] = make_float4(res[0], res[1], res[2], res[3]);
      op[1] = make_float4(res[4], res[5], res[6], res[7]);
    }
    #pragma unroll
    for (int k = 0; k < 8; ++k) {
      float s1 = res[k], s2 = res[k] * res[k];
      #pragma unroll
      for (int m = 2; m < 64; m <<= 1) { s1 += __shfl_xor(s1, m); s2 += __shfl_xor(s2, m); }
      if ((tid & 63) < 2) {
        atomicAdd(&sstat[base + k], s1);
        atomicAdd(&sstat[cD + base + k], s2);
      }
    }
    __syncthreads();
    if (tid < 2 * cD) atomicAdd(&stats[tid], sstat[tid]);
  }
}

// ---------------- launch ----------------
extern "C" void kernel_launch(void* const* d_in, const int* in_sizes, int n_in,
                              void* d_out, int out_size, void* d_ws, size_t ws_size,
                              hipStream_t stream) {
  const float* x_low    = (const float*)d_in[0];
  const float* z_std    = (const float*)d_in[1];
  const float* land     = (const float*)d_in[2];
  const int*   l2h_src  = (const int*)d_in[3];
  const int*   l2h_dst  = (const int*)d_in[4];
  const int*   hh_src   = (const int*)d_in[5];
  const int*   hh_dst   = (const int*)d_in[6];
  const float* gWih     = (const float*)d_in[7];
  const float* gWhh     = (const float*)d_in[8];
  const float* gbih     = (const float*)d_in[9];
  const float* gbhh     = (const float*)d_in[10];
  const float* dW       = (const float*)d_in[11];
  const float* db       = (const float*)d_in[12];
  const float* bn_enc_g = (const float*)d_in[13];
  const float* bn_enc_b = (const float*)d_in[14];
  const float* Wrel     = (const float*)d_in[15];
  const float* brel     = (const float*)d_in[16];
  const float* Wroot    = (const float*)d_in[17];
  const float* gat_Wl   = (const float*)d_in[18];
  const float* gat_bl   = (const float*)d_in[19];
  const float* gat_Wr   = (const float*)d_in[20];
  const float* gat_br   = (const float*)d_in[21];
  const float* gat_att  = (const float*)d_in[22];
  const float* gat_bias = (const float*)d_in[23];
  const float* bn_g     = (const float*)d_in[24];
  const float* bn_b     = (const float*)d_in[25];
  const float* pred_W   = (const float*)d_in[26];
  const float* pred_b   = (const float*)d_in[27];

  float* ws = (float*)d_ws;
  float* hs   = ws + OFF_HS;
  float* agg  = ws + OFF_AGG;
  float* enc  = ws + OFF_ENC;
  float* xA   = ws + OFF_XA;
  float* xB   = ws + OFF_XB;
  float* selfq= ws + OFF_XL;          // retired xl f32 slot -> self logits
  float* xr   = ws + OFF_XR;
  float* statsEnc = ws + OFF_STAT;
  float* statsX   = ws + OFF_STAT + 64;
  int* rp_hh  = (int*)(ws + OFF_RPH);
  int* src_hh = (int*)(ws + OFF_SRH);
  int* rp_l2h = (int*)(ws + OFF_RPL);
  int* src_l2h= (int*)(ws + OFF_SRL);
  int* cursor = (int*)(ws + OFF_CUR);
  int* part   = (int*)(ws + OFF_PART);
  unsigned short* xlb = (unsigned short*)(ws + OFF_XLB);
  // overlays in hs region (dead until k_gru)
  int*  cursor2 = (int*)(ws + OFF_CUR2);
  int*  part2   = (int*)(ws + OFF_PART2);
  int*  scur    = (int*)(ws + OFF_SCUR);
  int2* pairA   = (int2*)(ws + OFF_PAIRA);
  int2* pairB   = (int2*)(ws + OFF_PAIRB);

  hipMemsetAsync(statsEnc, 0, 256 * sizeof(float), stream);
  const int NODE_GRID = (cN_HIGH + 255) / 256;

  // --- radix-partition CSR build ---
  hipMemsetAsync(cursor,  0, cN_HIGH * sizeof(int), stream);
  hipMemsetAsync(cursor2, 0, cN_HIGH * sizeof(int), stream);
  k_initsc<<<1, 64, 0, stream>>>(scur);
  k_part<<<cPT_A + cPT_B, 256, 0, stream>>>(hh_src, hh_dst, l2h_src, l2h_dst,
                                            scur, pairA, pairB);
  k_hist2b<<<8 * (cHB_A + cHB_B), 256, 0, stream>>>(pairA, cursor, pairB, cursor2, scur);
  k_scan_local2<<<2 * SC_NB, 256, 0, stream>>>(cursor, rp_hh, part,
                                               cursor2, rp_l2h, part2);
  k_scan_top2<<<2, 256, 0, stream>>>(part, rp_hh + cN_HIGH,
                                     part2, rp_l2h + cN_HIGH);
  k_scan_add2<<<2 * SC_NB, 256, 0, stream>>>(rp_hh, part, cursor,
                                             rp_l2h, part2, cursor2);
  k_scatter2b<<<8 * (cHB_A + cHB_B), 256, 0, stream>>>(pairA, cursor, src_hh,
                                                       pairB, cursor2, src_l2h, scur);

  // --- encoder ---
  k_gru<<<cN_LOW / (2 * GW2), 256, 0, stream>>>(x_low, gWih, gWhh, gbih, gbhh, hs);
  k_dense<<<cN_LOW / cDN, 256, 0, stream>>>(hs, dW, db, enc, statsEnc);
  k_gather_csr<<<cN_HIGH / 8, 256, 0, stream>>>(enc, rp_l2h, src_l2h, statsEnc,
                                                bn_enc_g, bn_enc_b, agg);
  k_down<<<NODE_GRID, 256, 0, stream>>>(agg, z_std, land, Wrel, brel, Wroot, xA, statsX);

  const int EDGE_GRID = (2 * cN_HIGH + 255) / 256;
  // --- 5 GATv2 layers ---
  for (int i = 0; i < cNL; ++i) {
    float* xin  = (i & 1) ? xB : xA;
    float* xout = (i & 1) ? xA : xB;
    k_transform<<<NODE_GRID, 256, 0, stream>>>(xin, statsX + 32 * i,
                                               bn_g + 16 * i, bn_b + 16 * i,
                                               gat_Wl + 256 * i, gat_bl + 16 * i,
                                               gat_Wr + 256 * i, gat_br + 16 * i,
                                               gat_att + 16 * i,
                                               (i > 0) ? 1 : 0, selfq, xr, xlb);
    if (i < cNL - 1) {
      k_edge<0><<<EDGE_GRID, 256, 0, stream>>>(selfq, xr, xlb, rp_hh, src_hh,
                                               gat_att + 16 * i, gat_bias + 16 * i,
                                               nullptr, nullptr,
                                               xout, statsX + 32 * (i + 1), nullptr);
    } else {
      k_edge<1><<<EDGE_GRID, 256, 0, stream>>>(selfq, xr, xlb, rp_hh, src_hh,
                                               gat_att + 16 * i, gat_bias + 16 * i,
                                               pred_W, pred_b,
                                               nullptr, nullptr, (float*)d_out);
    }
  }
}

// Round 14
// 693.763 us; speedup vs baseline: 1.2222x; 1.2222x over previous
//
#include <hip/hip_runtime.h>
#include <hip/hip_bf16.h>
#include <cstddef>

// ---------------- problem constants ----------------
constexpr int cN_LOW  = 20000;
constexpr int cN_HIGH = 150000;
constexpr int cSEQ = 25;
constexpr int cHIN = 25;
constexpr int cHHID = 25;
constexpr int cENC = 32;
constexpr int cHIGH_IN = 7;
constexpr int cD = 16;
constexpr int cNL = 5;
constexpr int cE_L2H = 1350000;
constexpr int cE_HH = 1200000;
constexpr float cEPS = 1e-5f;
constexpr float cSLOPE = 0.2f;
constexpr float INV_NLOW  = 1.0f / (float)cN_LOW;
constexpr float INV_NHIGH = 1.0f / (float)cN_HIGH;

constexpr int cHSP = 640;     // padded hs row stride: 10 exact 64-f chunks

// scan geometry
constexpr int SC_ELEM = 1024;
constexpr int SC_NB   = (cN_HIGH + SC_ELEM - 1) / SC_ELEM;     // 147
static_assert(SC_NB <= 256, "top scan assumes <=256 partials");

// r14: sort-based CSR build. r13 counters: bucket reads went L2-resident
// (FETCH 79.5->10.8MB) but WRITE stayed ~100MB for 10.2MB payload across
// FOUR structurally different scatter impls. Invariant = 2.55M scattered
// 4B stores + atomic-with-return => each partial-line store becomes its
// own ~40B HBM transaction (write-no-allocate). Fix: make writes DENSE.
//   k_part64: 64-way split, block-reserved runs of 32 pairs (256B dense)
//   k_subhist: per-293-node block, LDS hist, dense deg write (no g-atomics)
//   k_sortcsr: LDS rank + LDS stage, one contiguous out-segment write
constexpr int cNCB = 64;                  // coarse buckets per graph
constexpr int cCB_NODES = 2344;           // 293*8; 64*2344 = 150016 >= N_HIGH
constexpr int cSUBN = 293;                // nodes per sort block
constexpr int cNSUB = 512;                // 512*293 = 150016
constexpr int cREG1_A = 19456;            // pairs/bucket region, hh  (+5.2 sigma)
constexpr int cREG1_B = 22016;            // l2h (+6.4 sigma)
constexpr int cCAP = 6144;                // LDS stage cap (mean ~2.3-2.6K)
constexpr int cEPB = 2048;                // edges per part block
constexpr int cPT_A = (cE_HH  + cEPB - 1) / cEPB;   // 586
constexpr int cPT_B = (cE_L2H + cEPB - 1) / cEPB;   // 660

// ---------------- workspace layout (4-byte element offsets) ----------------
constexpr size_t OFF_HS   = 0;                                   // [N_LOW*640]
constexpr size_t SZ_HS    = (size_t)cN_LOW * cHSP;
constexpr size_t OFF_AGG  = 0;                                   // alias (hs dead after k_dense)
constexpr size_t OFF_ENC  = OFF_HS + SZ_HS;                      // [N_LOW*32]
constexpr size_t SZ_ENC   = (size_t)cN_LOW * cENC;
constexpr size_t OFF_XA   = OFF_ENC + SZ_ENC;
constexpr size_t OFF_XB   = OFF_XA + (size_t)cN_HIGH * cD;
constexpr size_t OFF_XL   = OFF_XB + (size_t)cN_HIGH * cD;       // selfq [N_HIGH]
constexpr size_t OFF_XR   = OFF_XL + (size_t)cN_HIGH * cD;
constexpr size_t OFF_STAT = OFF_XR + (size_t)cN_HIGH * cD;       // [256]
constexpr size_t OFF_RPH  = OFF_STAT + 256;                      // rowptr_hh [N_HIGH+4]
constexpr size_t OFF_SRH  = OFF_RPH + cN_HIGH + 4;               // src_hh [E_HH]
constexpr size_t OFF_RPL  = OFF_SRH + cE_HH;                     // rowptr_l2h [N_HIGH+4]
constexpr size_t OFF_SRL  = OFF_RPL + cN_HIGH + 4;               // src_l2h [E_L2H]
constexpr size_t OFF_CUR  = OFF_SRL + cE_L2H;                    // cursor [N_HIGH] (hh)
constexpr size_t OFF_PART = OFF_CUR + cN_HIGH;                   // partials [256] (hh)
constexpr size_t OFF_XLB  = OFF_PART + 256;                      // xl bf16 [N_HIGH*16 ushort]
// overlays in the hs region (dead until k_gru, which launches after sortcsr)
constexpr size_t OFF_CUR2 = OFF_HS;                              // cursor2 [N_HIGH]
constexpr size_t OFF_PART2= OFF_HS + cN_HIGH + 16;               // partials2 [256]
constexpr size_t OFF_SCUR = OFF_PART2 + 256 + 16;                // shardCur [128]
constexpr size_t OFF_PAIRA= OFF_SCUR + 128;                      // int2[64*cREG1_A]
constexpr size_t OFF_PAIRB= OFF_PAIRA + (size_t)2 * cNCB * cREG1_A;
static_assert(OFF_PAIRB + (size_t)2 * cNCB * cREG1_B < SZ_HS, "pair buckets fit in hs");

typedef _Float16 half_t;
typedef half_t half2_t __attribute__((ext_vector_type(2)));

__device__ __forceinline__ float fast_sigmoid(float a) {
  return __builtin_amdgcn_rcpf(1.0f + __expf(-a));
}
__device__ __forceinline__ float fast_tanh(float a) {
  float t = __expf(-2.0f * a);
  return (1.0f - t) * __builtin_amdgcn_rcpf(1.0f + t);
}
__device__ __forceinline__ unsigned int f32_to_bf16_bits(float f) {
  unsigned int u = __float_as_uint(f);
  return (u + 0x7FFFu + ((u >> 16) & 1u)) >> 16;     // RNE
}
__device__ __forceinline__ void unpack8(uint4 v, float* x) {
  const unsigned int* w = (const unsigned int*)&v;
  #pragma unroll
  for (int m = 0; m < 4; ++m) {
    x[2 * m]     = __uint_as_float(w[m] << 16);
    x[2 * m + 1] = __uint_as_float(w[m] & 0xFFFF0000u);
  }
}

// ---------------- GRU kernel v8b (FROZEN: structural floor ~89us) ---------
constexpr int GW2 = 4;                // waves per block; 2 nodes/wave -> 8/block

__global__ __launch_bounds__(256, 4)
void k_gru(const float* __restrict__ x_low,
           const float* __restrict__ Wih, const float* __restrict__ Whh,
           const float* __restrict__ bih, const float* __restrict__ bhh,
           float* __restrict__ hs) {
  __shared__ __align__(16) half_t  sx   [GW2][2][25][32];   // x, then gi2 (12.8 KB)
  __shared__ __align__(16) half2_t sgi01[GW2][2][25][32];   // (gi0,gi1)   (25.6 KB)
  __shared__ __align__(16) half_t  sh   [GW2][2][2][32];    // h dbuf      ( 1.0 KB)

  int tid  = threadIdx.x;
  int wv   = tid >> 6;
  int lane = tid & 63;
  int hf   = lane >> 5;          // node half 0/1
  int j    = lane & 31;          // 0..31; active if < 25
  bool act = j < 25;
  int nw   = blockIdx.x * GW2 + wv;       // wave's node pair index
  int n    = nw * 2 + hf;                 // this half's node

  // ---- stage x (2 nodes, 1250 contiguous floats) into LDS as half ----
  {
    const float* xb = x_low + (size_t)nw * 1250;
    for (int i = lane; i < 1250; i += 64) {
      float v = xb[i];
      int node = i / 625;
      int rem  = i - node * 625;
      int t    = rem / 25;
      int k    = rem - t * 25;
      sx[wv][node][t][k] = (half_t)v;
    }
  }
  // zero pads (k=25..31) of sx and sh so b128 reads never see garbage
  if (!act) {
    #pragma unroll
    for (int t = 0; t < cSEQ; ++t) sx[wv][hf][t][j] = (half_t)0.0f;
    sh[wv][hf][0][j] = (half_t)0.0f;
    sh[wv][hf][1][j] = (half_t)0.0f;
  } else {
    sh[wv][hf][0][j] = (half_t)0.0f;     // h0 = 0
  }

  // ---- weight regs: first Wih (prologue), then Whh (loop) ----
  half2_t w0[13], w1[13], w2[13];
  float b0 = 0.0f, b1 = 0.0f, b2 = 0.0f;
  if (act) {
    #pragma unroll
    for (int k = 0; k < 13; ++k) {
      int i0 = 2 * k, i1 = 2 * k + 1;
      float a0 = Wih[j * 25 + i0];
      float a1 = (i1 < 25) ? Wih[j * 25 + i1] : 0.0f;
      float c0 = Wih[(25 + j) * 25 + i0];
      float c1 = (i1 < 25) ? Wih[(25 + j) * 25 + i1] : 0.0f;
      float d0 = Wih[(50 + j) * 25 + i0];
      float d1 = (i1 < 25) ? Wih[(50 + j) * 25 + i1] : 0.0f;
      w0[k] = half2_t{(half_t)a0, (half_t)a1};
      w1[k] = half2_t{(half_t)c0, (half_t)c1};
      w2[k] = half2_t{(half_t)d0, (half_t)d1};
    }
    b0 = bih[j]; b1 = bih[25 + j]; b2 = bih[50 + j];
  } else {
    #pragma unroll
    for (int k = 0; k < 13; ++k) { w0[k] = half2_t{(half_t)0.0f, (half_t)0.0f};
      w1[k] = w0[k]; w2[k] = w0[k]; }
  }

  // ---- prologue: gi[t] for all t; gi0/gi1 -> sgi01, gi2 -> sx[t] (overlay)
  for (int t = 0; t < cSEQ; ++t) {
    uint4 r0 = *(const uint4*)&sx[wv][hf][t][0];
    uint4 r1 = *(const uint4*)&sx[wv][hf][t][8];
    uint4 r2 = *(const uint4*)&sx[wv][hf][t][16];
    uint4 r3 = *(const uint4*)&sx[wv][hf][t][24];
    uint4 rr[4] = {r0, r1, r2, r3};
    const half2_t* vp = (const half2_t*)rr;
    float g0 = b0, g1 = b1, g2 = b2;
    #pragma unroll
    for (int k = 0; k < 13; ++k) {
      half2_t v = vp[k];
      g0 = __builtin_amdgcn_fdot2(w0[k], v, g0, false);
      g1 = __builtin_amdgcn_fdot2(w1[k], v, g1, false);
      g2 = __builtin_amdgcn_fdot2(w2[k], v, g2, false);
    }
    if (act) {
      sgi01[wv][hf][t][j] = half2_t{(half_t)g0, (half_t)g1};
      sx[wv][hf][t][j] = (half_t)g2;      // overlay: sx[t] row dead after reads above
    }
  }

  // ---- swap weights to Whh / bhh ----
  if (act) {
    #pragma unroll
    for (int k = 0; k < 13; ++k) {
      int i0 = 2 * k, i1 = 2 * k + 1;
      float a0 = Whh[j * 25 + i0];
      float a1 = (i1 < 25) ? Whh[j * 25 + i1] : 0.0f;
      float c0 = Whh[(25 + j) * 25 + i0];
      float c1 = (i1 < 25) ? Whh[(25 + j) * 25 + i1] : 0.0f;
      float d0 = Whh[(50 + j) * 25 + i0];
      float d1 = (i1 < 25) ? Whh[(50 + j) * 25 + i1] : 0.0f;
      w0[k] = half2_t{(half_t)a0, (half_t)a1};
      w1[k] = half2_t{(half_t)c0, (half_t)c1};
      w2[k] = half2_t{(half_t)d0, (half_t)d1};
    }
    b0 = bhh[j]; b1 = bhh[25 + j]; b2 = bhh[50 + j];
  }

  float* hrow = hs + (size_t)n * cHSP;
  if (j < 15) hrow[625 + j] = 0.0f;      // zero hs pad for dense chunks

  // ---- serial loop: h-side only, 2 nodes/wave ----
  float hprev = 0.0f;
  int p = 0;
  for (int t = 0; t < cSEQ; ++t) {
    uint4 r0 = *(const uint4*)&sh[wv][hf][p][0];
    uint4 r1 = *(const uint4*)&sh[wv][hf][p][8];
    uint4 r2 = *(const uint4*)&sh[wv][hf][p][16];
    uint4 r3 = *(const uint4*)&sh[wv][hf][p][24];
    uint4 rr[4] = {r0, r1, r2, r3};
    const half2_t* vp = (const half2_t*)rr;
    float g0 = b0, g1 = b1, g2 = b2;
    #pragma unroll
    for (int k = 0; k < 13; ++k) {
      half2_t v = vp[k];
      g0 = __builtin_amdgcn_fdot2(w0[k], v, g0, false);
      g1 = __builtin_amdgcn_fdot2(w1[k], v, g1, false);
      g2 = __builtin_amdgcn_fdot2(w2[k], v, g2, false);
    }
    if (act) {
      half2_t gv = sgi01[wv][hf][t][j];
      float gi0 = (float)gv.x;
      float gi1 = (float)gv.y;
      float gi2 = (float)sx[wv][hf][t][j];   // gi2 overlay
      float r  = fast_sigmoid(gi0 + g0);
      float z  = fast_sigmoid(gi1 + g1);
      float nn = fast_tanh(gi2 + r * g2);
      float hnew = (1.0f - z) * nn + z * hprev;
      hprev = hnew;
      sh[wv][hf][p ^ 1][j] = (half_t)hnew;
      hrow[t * 25 + j] = hnew;
    }
    p ^= 1;
  }
}

// ---------------- dense 625->32 + relu + BN stats (v4) ----------------
constexpr int cDN = 32;      // nodes per block
__global__ __launch_bounds__(256)
void k_dense(const float* __restrict__ hs, const float* __restrict__ W,
             const float* __restrict__ b, float* __restrict__ enc,
             float* __restrict__ statsEnc) {
  __shared__ __align__(16) float sW2[640 * 32];        // 80 KB: [f][e2-pair]
  __shared__ __align__(16) float sH[2][cDN * 68];      // 17.4 KB
  __shared__ float sstat[2 * cENC];
  int tid = threadIdx.x;
  for (int i = tid; i < 32 * 625; i += 256) {
    int e = i / 625, f = i % 625;
    sW2[f * 32 + (e & 15) * 2 + (e >> 4)] = W[i];
  }
  for (int i = tid; i < 32 * 15; i += 256)
    sW2[(625 + (i >> 5)) * 32 + (i & 31)] = 0.0f;
  if (tid < 2 * cENC) sstat[tid] = 0.0f;

  int e2 = tid & 15;
  int ng = (tid >> 4) & 3;
  int w  = tid >> 6;
  int rA = 8 * w + 2 * ng;
  int rB = rA + 1;
  size_t nbase = (size_t)blockIdx.x * cDN;

  int srow = tid >> 4;
  int sf4  = (tid & 15) * 4;
  const float* hsb = hs + nbase * cHSP;
  {
    float4 v0 = *(const float4*)(hsb + (size_t)srow * cHSP + sf4);
    float4 v1 = *(const float4*)(hsb + (size_t)(srow + 16) * cHSP + sf4);
    *(float4*)&sH[0][srow * 68 + sf4] = v0;
    *(float4*)&sH[0][(srow + 16) * 68 + sf4] = v1;
  }
  __syncthreads();

  float a00 = 0.0f, a01 = 0.0f, a10 = 0.0f, a11 = 0.0f;
  for (int c = 0; c < 10; ++c) {
    int buf = c & 1;
    if (c + 1 < 10) {
      const float* src = hsb + (c + 1) * 64;
      float4 v0 = *(const float4*)(src + (size_t)srow * cHSP + sf4);
      float4 v1 = *(const float4*)(src + (size_t)(srow + 16) * cHSP + sf4);
      *(float4*)&sH[buf ^ 1][srow * 68 + sf4] = v0;
      *(float4*)&sH[buf ^ 1][(srow + 16) * 68 + sf4] = v1;
    }
    const float* WC = sW2 + c * 64 * 32;
    #pragma unroll
    for (int fg = 0; fg < 16; ++fg) {
      float4 hA = *(const float4*)&sH[buf][rA * 68 + fg * 4];
      float4 hB = *(const float4*)&sH[buf][rB * 68 + fg * 4];
      const float* ha = (const float*)&hA;
      const float* hb = (const float*)&hB;
      #pragma unroll
      for (int k = 0; k < 4; ++k) {
        float2 wv = *(const float2*)&WC[(fg * 4 + k) * 32 + e2 * 2];
        a00 += wv.x * ha[k]; a01 += wv.y * ha[k];
        a10 += wv.x * hb[k]; a11 += wv.y * hb[k];
      }
    }
    __syncthreads();
  }
  float blo = b[e2], bhi = b[e2 + 16];
  float v00 = fmaxf(a00 + blo, 0.0f);
  float v01 = fmaxf(a01 + bhi, 0.0f);
  float v10 = fmaxf(a10 + blo, 0.0f);
  float v11 = fmaxf(a11 + bhi, 0.0f);
  size_t nA = nbase + rA, nB = nbase + rB;
  enc[nA * cENC + e2]      = v00;
  enc[nA * cENC + e2 + 16] = v01;
  enc[nB * cENC + e2]      = v10;
  enc[nB * cENC + e2 + 16] = v11;

  float s1lo = v00 + v10, s1hi = v01 + v11;
  float s2lo = v00 * v00 + v10 * v10, s2hi = v01 * v01 + v11 * v11;
  s1lo += __shfl_xor(s1lo, 16); s1hi += __shfl_xor(s1hi, 16);
  s2lo += __shfl_xor(s2lo, 16); s2hi += __shfl_xor(s2hi, 16);
  s1lo += __shfl_xor(s1lo, 32); s1hi += __shfl_xor(s1hi, 32);
  s2lo += __shfl_xor(s2lo, 32); s2hi += __shfl_xor(s2hi, 32);
  if ((tid & 63) < 16) {
    atomicAdd(&sstat[e2], s1lo);
    atomicAdd(&sstat[e2 + 16], s1hi);
    atomicAdd(&sstat[cENC + e2], s2lo);
    atomicAdd(&sstat[cENC + e2 + 16], s2hi);
  }
  __syncthreads();
  if (tid < 2 * cENC) atomicAdd(&statsEnc[tid], sstat[tid]);
}

// ---------------- sort-based CSR build (r14) ----------------
__global__ void k_initsc(int* __restrict__ scur) {
  int t = threadIdx.x;
  if (t < cNCB) scur[t] = t * cREG1_A;
  else if (t < 2 * cNCB) scur[t] = (t - cNCB) * cREG1_B;
}

// 64-way split with block-reserved dense runs (32 pairs = 256B per bucket)
__global__ __launch_bounds__(256)
void k_part64(const int* __restrict__ srcA, const int* __restrict__ dstA,
              const int* __restrict__ srcB, const int* __restrict__ dstB,
              int* __restrict__ scur, int2* __restrict__ pairA, int2* __restrict__ pairB) {
  __shared__ int cnt[cNCB];
  __shared__ int base_[cNCB];
  int bid = blockIdx.x;
  const int* src; const int* dst; int nE; int2* pair; int* sc;
  if (bid < cPT_A) { src = srcA; dst = dstA; nE = cE_HH; pair = pairA; sc = scur; }
  else { bid -= cPT_A; src = srcB; dst = dstB; nE = cE_L2H; pair = pairB; sc = scur + cNCB; }
  int tid = threadIdx.x;
  for (int i = tid; i < cNCB; i += 256) cnt[i] = 0;
  __syncthreads();
  int e0 = bid * cEPB;
  int myd[8], mys[8], myb[8];
  #pragma unroll
  for (int k = 0; k < 8; ++k) {
    int e = e0 + k * 256 + tid;
    if (e < nE) {
      int d = __builtin_nontemporal_load(dst + e);
      int s = __builtin_nontemporal_load(src + e);
      myd[k] = d; mys[k] = s;
      int b = d / cCB_NODES;
      myb[k] = b;
      atomicAdd(&cnt[b], 1);
    } else myb[k] = -1;
  }
  __syncthreads();
  for (int i = tid; i < cNCB; i += 256) base_[i] = atomicAdd(&sc[i], cnt[i]);
  __syncthreads();
  for (int i = tid; i < cNCB; i += 256) cnt[i] = 0;    // reuse as rank cursors
  __syncthreads();
  #pragma unroll
  for (int k = 0; k < 8; ++k) {
    if (myb[k] >= 0) {
      int r = atomicAdd(&cnt[myb[k]], 1);
      pair[base_[myb[k]] + r] = make_int2(mys[k], myd[k]);
    }
  }
}

// per-293-node block: LDS hist over its coarse bucket, dense deg write.
// bid mapping: cb = bid&63 -> bid%8 = cb%8, so the 8 sibling blocks of a
// coarse bucket land on ONE XCD (bucket stays in that XCD's L2).
__global__ __launch_bounds__(256)
void k_subhist(const int2* __restrict__ pairA, int* __restrict__ degA,
               const int2* __restrict__ pairB, int* __restrict__ degB,
               const int* __restrict__ scur) {
  __shared__ int h[cSUBN];
  int bid = blockIdx.x;
  const int2* pair; int* deg; const int* sc; int reg;
  if (bid < cNSUB) { pair = pairA; deg = degA; sc = scur; reg = cREG1_A; }
  else { bid -= cNSUB; pair = pairB; deg = degB; sc = scur + cNCB; reg = cREG1_B; }
  int cb = bid & 63;
  int s  = bid >> 6;
  int lo = cb * cCB_NODES + s * cSUBN;
  int hi = min(lo + cSUBN, cN_HIGH);
  if (lo >= cN_HIGH) return;
  int tid = threadIdx.x;
  for (int i = tid; i < cSUBN; i += 256) h[i] = 0;
  __syncthreads();
  int fill = sc[cb] - cb * reg;
  const int2* bk = pair + (size_t)cb * reg;
  for (int i = tid; i < fill; i += 256) {
    int d = bk[i].y;
    if (d >= lo && d < hi) atomicAdd(&h[d - lo], 1);
  }
  __syncthreads();
  for (int i = tid; i < hi - lo; i += 256) deg[lo + i] = h[i];
}

// per-293-node block: LDS rank + LDS stage, single contiguous out write
__global__ __launch_bounds__(256)
void k_sortcsr(const int2* __restrict__ pairA, const int* __restrict__ rpA,
               int* __restrict__ curA, int* __restrict__ outA,
               const int2* __restrict__ pairB, const int* __restrict__ rpB,
               int* __restrict__ curB, int* __restrict__ outB,
               const int* __restrict__ scur) {
  __shared__ int rp[cSUBN + 1];
  __shared__ int rc[cSUBN];
  __shared__ int stage[cCAP];
  int bid = blockIdx.x;
  const int2* pair; const int* rowptr; int* cur; int* out; const int* sc; int reg;
  if (bid < cNSUB) { pair = pairA; rowptr = rpA; cur = curA; out = outA; sc = scur; reg = cREG1_A; }
  else { bid -= cNSUB; pair = pairB; rowptr = rpB; cur = curB; out = outB; sc = scur + cNCB; reg = cREG1_B; }
  int cb = bid & 63;
  int s  = bid >> 6;
  int lo = cb * cCB_NODES + s * cSUBN;
  int hi = min(lo + cSUBN, cN_HIGH);
  if (lo >= cN_HIGH) return;
  int nn = hi - lo;
  int tid = threadIdx.x;
  for (int i = tid; i <= nn; i += 256) rp[i] = rowptr[lo + i];
  for (int i = tid; i < nn; i += 256) rc[i] = 0;
  __syncthreads();
  int gbase = rp[0];
  int count = rp[nn] - gbase;
  int fill = sc[cb] - cb * reg;
  const int2* bk = pair + (size_t)cb * reg;
  if (count <= cCAP) {
    for (int i = tid; i < fill; i += 256) {
      int2 p = bk[i];
      int d = p.y;
      if (d >= lo && d < hi) {
        int j = d - lo;
        int r = atomicAdd(&rc[j], 1);
        stage[rp[j] - gbase + r] = p.x;
      }
    }
    __syncthreads();
    for (int i = tid; i < count; i += 256) out[gbase + i] = stage[i];
  } else {
    // overflow fallback (never expected: cap is +79 sigma); cursor = rowptr copy
    for (int i = tid; i < fill; i += 256) {
      int2 p = bk[i];
      int d = p.y;
      if (d >= lo && d < hi) {
        int pos = atomicAdd(&cur[d], 1);
        out[pos] = p.x;
      }
    }
  }
}

__global__ void k_scan_local2(const int* __restrict__ degA, int* __restrict__ outA,
                              int* __restrict__ partA,
                              const int* __restrict__ degB, int* __restrict__ outB,
                              int* __restrict__ partB) {
  int bid = blockIdx.x;
  const int* deg; int* out; int* partial;
  if (bid < SC_NB) { deg = degA; out = outA; partial = partA; }
  else { bid -= SC_NB; deg = degB; out = outB; partial = partB; }
  const int n = cN_HIGH;
  int tid = threadIdx.x;
  int base = bid * SC_ELEM + tid * 4;
  int4 v = make_int4(0, 0, 0, 0);
  if (base + 3 < n) v = *(const int4*)(deg + base);
  else { int* pv = (int*)&v; for (int k = 0; k < 4; ++k) if (base + k < n) pv[k] = deg[base + k]; }
  int tsum = v.x + v.y + v.z + v.w;
  int lane = tid & 63;
  int inc = tsum;
  #pragma unroll
  for (int o = 1; o < 64; o <<= 1) { int t = __shfl_up(inc, o); if (lane >= o) inc += t; }
  __shared__ int wtot[4];
  if (lane == 63) wtot[tid >> 6] = inc;
  __syncthreads();
  int w = tid >> 6, wbase = 0;
  #pragma unroll
  for (int k = 0; k < 3; ++k) if (k < w) wbase += wtot[k];
  int ebase = wbase + inc - tsum;
  int4 o4;
  o4.x = ebase; o4.y = ebase + v.x; o4.z = o4.y + v.y; o4.w = o4.z + v.z;
  if (base + 3 < n) *(int4*)(out + base) = o4;
  else { int* po = (int*)&o4; for (int k = 0; k < 4; ++k) if (base + k < n) out[base + k] = po[k]; }
  if (tid == 255) partial[bid] = wbase + inc;
}

__global__ void k_scan_top2(int* __restrict__ partA, int* __restrict__ totalA,
                            int* __restrict__ partB, int* __restrict__ totalB) {
  int* partial = (blockIdx.x == 0) ? partA : partB;
  int* total_out = (blockIdx.x == 0) ? totalA : totalB;
  const int nb = SC_NB;
  __shared__ int sd[256];
  int tid = threadIdx.x;
  int v = (tid < nb) ? partial[tid] : 0;
  sd[tid] = v;
  __syncthreads();
  for (int off = 1; off < 256; off <<= 1) {
    int t = (tid >= off) ? sd[tid - off] : 0;
    __syncthreads();
    sd[tid] += t;
    __syncthreads();
  }
  if (tid < nb) partial[tid] = sd[tid] - v;
  if (tid == 255) *total_out = sd[255];
}

__global__ void k_scan_add2(int* __restrict__ rpA, const int* __restrict__ partA,
                            int* __restrict__ curA,
                            int* __restrict__ rpB, const int* __restrict__ partB,
                            int* __restrict__ curB) {
  int bid = blockIdx.x;
  int* rowptr; const int* partial; int* cursor;
  if (bid < SC_NB) { rowptr = rpA; partial = partA; cursor = curA; }
  else { bid -= SC_NB; rowptr = rpB; partial = partB; cursor = curB; }
  const int n = cN_HIGH;
  int base = bid * SC_ELEM + threadIdx.x * 4;
  int add = partial[bid];
  if (base + 3 < n) {
    int4 v = *(int4*)(rowptr + base);
    v.x += add; v.y += add; v.z += add; v.w += add;
    *(int4*)(rowptr + base) = v;
    *(int4*)(cursor + base) = v;
  } else {
    for (int k = 0; k < 4; ++k)
      if (base + k < n) { int t = rowptr[base + k] + add; rowptr[base + k] = t; cursor[base + k] = t; }
  }
}

// ---------------- l2h gather via CSR (2-way unrolled) ----------------
__global__ void k_gather_csr(const float* __restrict__ enc, const int* __restrict__ rowptr,
                             const int* __restrict__ srcs, const float* __restrict__ statsEnc,
                             const float* __restrict__ g, const float* __restrict__ bb,
                             float* __restrict__ agg) {
  __shared__ float ssc[cENC], ssh[cENC];
  int tid = threadIdx.x;
  if (tid < cENC) {
    float m = statsEnc[tid] * INV_NLOW;
    float var = statsEnc[cENC + tid] * INV_NLOW - m * m;
    float sc = g[tid] * rsqrtf(var + cEPS);
    ssc[tid] = sc;
    ssh[tid] = bb[tid] - m * sc;
  }
  __syncthreads();
  int c = tid & 31;
  int n = blockIdx.x * 8 + (tid >> 5);
  int lo = rowptr[n], hi = rowptr[n + 1];
  float sum = 0.0f;
  int i = lo;
  for (; i + 1 < hi; i += 2) {
    int s0 = srcs[i], s1 = srcs[i + 1];
    sum += enc[(size_t)s0 * cENC + c] + enc[(size_t)s1 * cENC + c];
  }
  if (i < hi) sum += enc[(size_t)srcs[i] * cENC + c];
  float deg = (float)(hi - lo);
  agg[(size_t)n * cENC + c] = (ssc[c] * sum + deg * ssh[c]) / fmaxf(deg, 1.0f);
}

// ---------------- down-projection + BN0 stats ----------------
__global__ void k_down(const float* __restrict__ agg,
                       const float* __restrict__ z_std, const float* __restrict__ land,
                       const float* __restrict__ Wrel, const float* __restrict__ brel,
                       const float* __restrict__ Wroot,
                       float* __restrict__ x0, float* __restrict__ stats) {
  __shared__ float sstat[2 * cD];
  __shared__ float sWrel[cD * cENC], sWroot[cD * cHIGH_IN], sbrel[cD];
  int tid = threadIdx.x;
  if (tid < 2 * cD) sstat[tid] = 0.0f;
  for (int i = tid; i < cD * cENC; i += 256) sWrel[i] = Wrel[i];
  if (tid < cD * cHIGH_IN) sWroot[tid] = Wroot[tid];
  if (tid < cD) sbrel[tid] = brel[tid];
  __syncthreads();

  int n = blockIdx.x * 256 + tid;
  bool valid = n < cN_HIGH;
  float a[cENC], zz[cHIGH_IN];
  if (valid) {
    const float4* ar4 = (const float4*)(agg + (size_t)n * cENC);
    #pragma unroll
    for (int k = 0; k < cENC / 4; ++k) {
      float4 t4 = ar4[k];
      a[4*k] = t4.x; a[4*k+1] = t4.y; a[4*k+2] = t4.z; a[4*k+3] = t4.w;
    }
    #pragma unroll
    for (int k = 0; k < 6; ++k) zz[k] = z_std[(size_t)n * 6 + k];
    zz[6] = land[n];
  } else {
    #pragma unroll
    for (int k = 0; k < cENC; ++k) a[k] = 0.0f;
    #pragma unroll
    for (int k = 0; k < cHIGH_IN; ++k) zz[k] = 0.0f;
  }
  int lane = tid & 63;
  #pragma unroll
  for (int d = 0; d < cD; ++d) {
    float acc = sbrel[d];
    #pragma unroll
    for (int k = 0; k < cENC; ++k) acc += a[k] * sWrel[d * cENC + k];
    #pragma unroll
    for (int k = 0; k < cHIGH_IN; ++k) acc += zz[k] * sWroot[d * cHIGH_IN + k];
    if (valid) x0[(size_t)n * cD + d] = acc;
    float v = valid ? acc : 0.0f;
    float s1 = v, s2 = v * v;
    #pragma unroll
    for (int o = 32; o > 0; o >>= 1) { s1 += __shfl_down(s1, o); s2 += __shfl_down(s2, o); }
    if (lane == 0) { atomicAdd(&sstat[d], s1); atomicAdd(&sstat[cD + d], s2); }
  }
  __syncthreads();
  if (tid < 2 * cD) atomicAdd(&stats[tid], sstat[tid]);
}

// ---------------- GAT node transform (emits xr, xlb bf16, self-logit) -----
__global__ void k_transform(const float* __restrict__ xin, const float* __restrict__ stats,
                            const float* __restrict__ g, const float* __restrict__ b,
                            const float* __restrict__ Wl, const float* __restrict__ bl,
                            const float* __restrict__ Wr, const float* __restrict__ br,
                            const float* __restrict__ att,
                            int applyRelu,
                            float* __restrict__ selfq, float* __restrict__ xr,
                            unsigned short* __restrict__ xlb) {
  __shared__ float ssc[cD], ssh[cD], sWl[cD * cD], sWr[cD * cD], sbl[cD], sbr[cD], satt[cD];
  int tid = threadIdx.x;
  if (tid < cD) {
    float m = stats[tid] * INV_NHIGH;
    float v = stats[cD + tid] * INV_NHIGH - m * m;
    float sc = g[tid] * rsqrtf(v + cEPS);
    ssc[tid] = sc;
    ssh[tid] = b[tid] - m * sc;
    sbl[tid] = bl[tid];
    sbr[tid] = br[tid];
    satt[tid] = att[tid];
  }
  if (tid < cD * cD) { sWl[tid] = Wl[tid]; sWr[tid] = Wr[tid]; }
  __syncthreads();

  int n = blockIdx.x * 256 + tid;
  if (n >= cN_HIGH) return;
  float act[cD];
  const float* xp = xin + (size_t)n * cD;
  #pragma unroll
  for (int d = 0; d < cD; ++d) {
    float v = xp[d] * ssc[d] + ssh[d];
    if (applyRelu) v = fmaxf(v, 0.0f);
    act[d] = v;
  }
  float alv[cD], arv[cD];
  float* xrp = xr + (size_t)n * cD;
  #pragma unroll
  for (int d = 0; d < cD; ++d) {
    float al = sbl[d], ar = sbr[d];
    #pragma unroll
    for (int k = 0; k < cD; ++k) { al += act[k] * sWl[d * cD + k]; ar += act[k] * sWr[d * cD + k]; }
    alv[d] = al;
    arv[d] = ar;
    xrp[d] = ar;
  }
  // self-loop attention logit
  float qq = 0.0f;
  #pragma unroll
  for (int d = 0; d < cD; ++d) {
    float u = alv[d] + arv[d];
    u = fmaxf(u, cSLOPE * u);
    qq += u * satt[d];
  }
  selfq[n] = qq;

  uint4 w0, w1;
  unsigned int* pw = (unsigned int*)&w0;
  #pragma unroll
  for (int k = 0; k < 4; ++k)
    pw[k] = f32_to_bf16_bits(alv[2 * k]) | (f32_to_bf16_bits(alv[2 * k + 1]) << 16);
  unsigned int* pw1 = (unsigned int*)&w1;
  #pragma unroll
  for (int k = 0; k < 4; ++k)
    pw1[k] = f32_to_bf16_bits(alv[8 + 2 * k]) | (f32_to_bf16_bits(alv[8 + 2 * k + 1]) << 16);
  uint4* dst = (uint4*)(xlb + (size_t)n * cD);
  dst[0] = w0;
  dst[1] = w1;
}

// ---------------- fused GAT edge pass v6: no xl array, 4-way gathers ------
template<int FINAL>
__global__ __launch_bounds__(256)
void k_edge(const float* __restrict__ selfq, const float* __restrict__ xr,
            const unsigned short* __restrict__ xlb,
            const int* __restrict__ rowptr, const int* __restrict__ srcs,
            const float* __restrict__ att, const float* __restrict__ bias,
            const float* __restrict__ pW, const float* __restrict__ pb,
            float* __restrict__ xout, float* __restrict__ stats,
            float* __restrict__ out) {
  __shared__ float sstat[2 * cD];
  int tid = threadIdx.x;
  if (!FINAL) {
    if (tid < 2 * cD) sstat[tid] = 0.0f;
    __syncthreads();
  }

  int half = tid & 1;
  int n = (blockIdx.x * 256 + tid) >> 1;
  bool valid = n < cN_HIGH;
  int base = half * 8;

  float av[8];
  #pragma unroll
  for (int k = 0; k < 8; ++k) av[k] = att[base + k];

  const uint4* xl4 = (const uint4*)xlb;
  float xrv[8], num[8];
  float denom = 1.0f;
  int lo = 0, hi = 0;
  if (valid) {
    #pragma unroll
    for (int k = 0; k < 2; ++k) {
      float4 t = *(const float4*)(xr + (size_t)n * cD + base + 4 * k);
      xrv[4*k] = t.x; xrv[4*k+1] = t.y; xrv[4*k+2] = t.z; xrv[4*k+3] = t.w;
    }
    // self contribution: own bf16 row + precomputed logit
    uint4 vs = xl4[(size_t)n * 2 + half];
    float xsv[8];
    unpack8(vs, xsv);
    float e = __expf(selfq[n]);
    denom = e;
    #pragma unroll
    for (int k = 0; k < 8; ++k) num[k] = e * xsv[k];
    lo = rowptr[n]; hi = rowptr[n + 1];
  } else {
    #pragma unroll
    for (int k = 0; k < 8; ++k) { num[k] = 0.0f; xrv[k] = 0.0f; }
  }

  int i = lo;
  for (; i + 3 < hi; i += 4) {
    int s0 = srcs[i], s1 = srcs[i + 1], s2 = srcs[i + 2], s3 = srcs[i + 3];
    uint4 v0 = xl4[(size_t)s0 * 2 + half];
    uint4 v1 = xl4[(size_t)s1 * 2 + half];
    uint4 v2 = xl4[(size_t)s2 * 2 + half];
    uint4 v3 = xl4[(size_t)s3 * 2 + half];
    float x0[8], x1[8], x2[8], x3[8];
    unpack8(v0, x0);
    unpack8(v1, x1);
    unpack8(v2, x2);
    unpack8(v3, x3);
    float q0 = 0.0f, q1 = 0.0f, q2 = 0.0f, q3 = 0.0f;
    #pragma unroll
    for (int k = 0; k < 8; ++k) {
      float u0 = x0[k] + xrv[k]; u0 = fmaxf(u0, cSLOPE * u0);
      float u1 = x1[k] + xrv[k]; u1 = fmaxf(u1, cSLOPE * u1);
      float u2 = x2[k] + xrv[k]; u2 = fmaxf(u2, cSLOPE * u2);
      float u3 = x3[k] + xrv[k]; u3 = fmaxf(u3, cSLOPE * u3);
      q0 += u0 * av[k]; q1 += u1 * av[k]; q2 += u2 * av[k]; q3 += u3 * av[k];
    }
    q0 += __shfl_xor(q0, 1);
    q1 += __shfl_xor(q1, 1);
    q2 += __shfl_xor(q2, 1);
    q3 += __shfl_xor(q3, 1);
    float e0 = __expf(q0), e1 = __expf(q1), e2 = __expf(q2), e3 = __expf(q3);
    denom += (e0 + e1) + (e2 + e3);
    #pragma unroll
    for (int k = 0; k < 8; ++k)
      num[k] += (e0 * x0[k] + e1 * x1[k]) + (e2 * x2[k] + e3 * x3[k]);
  }
  for (; i + 1 < hi; i += 2) {
    int s0 = srcs[i], s1 = srcs[i + 1];
    uint4 v0 = xl4[(size_t)s0 * 2 + half];
    uint4 v1 = xl4[(size_t)s1 * 2 + half];
    float x0[8], x1[8];
    unpack8(v0, x0);
    unpack8(v1, x1);
    float q0 = 0.0f, q1 = 0.0f;
    #pragma unroll
    for (int k = 0; k < 8; ++k) {
      float u0 = x0[k] + xrv[k]; u0 = fmaxf(u0, cSLOPE * u0);
      float u1 = x1[k] + xrv[k]; u1 = fmaxf(u1, cSLOPE * u1);
      q0 += u0 * av[k]; q1 += u1 * av[k];
    }
    q0 += __shfl_xor(q0, 1);
    q1 += __shfl_xor(q1, 1);
    float e0 = __expf(q0), e1 = __expf(q1);
    denom += e0 + e1;
    #pragma unroll
    for (int k = 0; k < 8; ++k) num[k] += e0 * x0[k] + e1 * x1[k];
  }
  if (i < hi) {
    int s = srcs[i];
    uint4 v = xl4[(size_t)s * 2 + half];
    float x[8];
    unpack8(v, x);
    float qq = 0.0f;
    #pragma unroll
    for (int k = 0; k < 8; ++k) {
      float u = x[k] + xrv[k]; u = fmaxf(u, cSLOPE * u);
      qq += u * av[k];
    }
    qq += __shfl_xor(qq, 1);
    float e = __expf(qq);
    denom += e;
    #pragma unroll
    for (int k = 0; k < 8; ++k) num[k] += e * x[k];
  }

  float cnt = (float)(hi - lo + 1);
  float inv = __builtin_amdgcn_rcpf(denom * cnt);
  float res[8];
  #pragma unroll
  for (int k = 0; k < 8; ++k)
    res[k] = valid ? (num[k] * inv + bias[base + k]) : 0.0f;

  if (FINAL) {
    float t = 0.0f;
    #pragma unroll
    for (int k = 0; k < 8; ++k) t += fmaxf(res[k], 0.0f) * pW[base + k];
    t += __shfl_xor(t, 1);
    if (valid && half == 0) out[n] = t + pb[0];
  } else {
    if (valid) {
      float4* op = (float4*)(xout + (size_t)n * cD + base);
      op[0] = make_float4(res[0], res[1], res[2], res[3]);
      op[1] = make_float4(res[4], res[5], res[6], res[7]);
    }
    #pragma unroll
    for (int k = 0; k < 8; ++k) {
      float s1 = res[k], s2 = res[k] * res[k];
      #pragma unroll
      for (int m = 2; m < 64; m <<= 1) { s1 += __shfl_xor(s1, m); s2 += __shfl_xor(s2, m); }
      if ((tid & 63) < 2) {
        atomicAdd(&sstat[base + k], s1);
        atomicAdd(&sstat[cD + base + k], s2);
      }
    }
    __syncthreads();
    if (tid < 2 * cD) atomicAdd(&stats[tid], sstat[tid]);
  }
}

// ---------------- launch ----------------
extern "C" void kernel_launch(void* const* d_in, const int* in_sizes, int n_in,
                              void* d_out, int out_size, void* d_ws, size_t ws_size,
                              hipStream_t stream) {
  const float* x_low    = (const float*)d_in[0];
  const float* z_std    = (const float*)d_in[1];
  const float* land     = (const float*)d_in[2];
  const int*   l2h_src  = (const int*)d_in[3];
  const int*   l2h_dst  = (const int*)d_in[4];
  const int*   hh_src   = (const int*)d_in[5];
  const int*   hh_dst   = (const int*)d_in[6];
  const float* gWih     = (const float*)d_in[7];
  const float* gWhh     = (const float*)d_in[8];
  const float* gbih     = (const float*)d_in[9];
  const float* gbhh     = (const float*)d_in[10];
  const float* dW       = (const float*)d_in[11];
  const float* db       = (const float*)d_in[12];
  const float* bn_enc_g = (const float*)d_in[13];
  const float* bn_enc_b = (const float*)d_in[14];
  const float* Wrel     = (const float*)d_in[15];
  const float* brel     = (const float*)d_in[16];
  const float* Wroot    = (const float*)d_in[17];
  const float* gat_Wl   = (const float*)d_in[18];
  const float* gat_bl   = (const float*)d_in[19];
  const float* gat_Wr   = (const float*)d_in[20];
  const float* gat_br   = (const float*)d_in[21];
  const float* gat_att  = (const float*)d_in[22];
  const float* gat_bias = (const float*)d_in[23];
  const float* bn_g     = (const float*)d_in[24];
  const float* bn_b     = (const float*)d_in[25];
  const float* pred_W   = (const float*)d_in[26];
  const float* pred_b   = (const float*)d_in[27];

  float* ws = (float*)d_ws;
  float* hs   = ws + OFF_HS;
  float* agg  = ws + OFF_AGG;
  float* enc  = ws + OFF_ENC;
  float* xA   = ws + OFF_XA;
  float* xB   = ws + OFF_XB;
  float* selfq= ws + OFF_XL;          // retired xl f32 slot -> self logits
  float* xr   = ws + OFF_XR;
  float* statsEnc = ws + OFF_STAT;
  float* statsX   = ws + OFF_STAT + 64;
  int* rp_hh  = (int*)(ws + OFF_RPH);
  int* src_hh = (int*)(ws + OFF_SRH);
  int* rp_l2h = (int*)(ws + OFF_RPL);
  int* src_l2h= (int*)(ws + OFF_SRL);
  int* cursor = (int*)(ws + OFF_CUR);
  int* part   = (int*)(ws + OFF_PART);
  unsigned short* xlb = (unsigned short*)(ws + OFF_XLB);
  // overlays in hs region (dead until k_gru)
  int*  cursor2 = (int*)(ws + OFF_CUR2);
  int*  part2   = (int*)(ws + OFF_PART2);
  int*  scur    = (int*)(ws + OFF_SCUR);
  int2* pairA   = (int2*)(ws + OFF_PAIRA);
  int2* pairB   = (int2*)(ws + OFF_PAIRB);

  hipMemsetAsync(statsEnc, 0, 256 * sizeof(float), stream);
  const int NODE_GRID = (cN_HIGH + 255) / 256;

  // --- sort-based CSR build (no cursor memsets: subhist writes all deg) ---
  k_initsc<<<1, 128, 0, stream>>>(scur);
  k_part64<<<cPT_A + cPT_B, 256, 0, stream>>>(hh_src, hh_dst, l2h_src, l2h_dst,
                                              scur, pairA, pairB);
  k_subhist<<<2 * cNSUB, 256, 0, stream>>>(pairA, cursor, pairB, cursor2, scur);
  k_scan_local2<<<2 * SC_NB, 256, 0, stream>>>(cursor, rp_hh, part,
                                               cursor2, rp_l2h, part2);
  k_scan_top2<<<2, 256, 0, stream>>>(part, rp_hh + cN_HIGH,
                                     part2, rp_l2h + cN_HIGH);
  k_scan_add2<<<2 * SC_NB, 256, 0, stream>>>(rp_hh, part, cursor,
                                             rp_l2h, part2, cursor2);
  k_sortcsr<<<2 * cNSUB, 256, 0, stream>>>(pairA, rp_hh, cursor, src_hh,
                                           pairB, rp_l2h, cursor2, src_l2h, scur);

  // --- encoder ---
  k_gru<<<cN_LOW / (2 * GW2), 256, 0, stream>>>(x_low, gWih, gWhh, gbih, gbhh, hs);
  k_dense<<<cN_LOW / cDN, 256, 0, stream>>>(hs, dW, db, enc, statsEnc);
  k_gather_csr<<<cN_HIGH / 8, 256, 0, stream>>>(enc, rp_l2h, src_l2h, statsEnc,
                                                bn_enc_g, bn_enc_b, agg);
  k_down<<<NODE_GRID, 256, 0, stream>>>(agg, z_std, land, Wrel, brel, Wroot, xA, statsX);

  const int EDGE_GRID = (2 * cN_HIGH + 255) / 256;
  // --- 5 GATv2 layers ---
  for (int i = 0; i < cNL; ++i) {
    float* xin  = (i & 1) ? xB : xA;
    float* xout = (i & 1) ? xA : xB;
    k_transform<<<NODE_GRID, 256, 0, stream>>>(xin, statsX + 32 * i,
                                               bn_g + 16 * i, bn_b + 16 * i,
                                               gat_Wl + 256 * i, gat_bl + 16 * i,
                                               gat_Wr + 256 * i, gat_br + 16 * i,
                                               gat_att + 16 * i,
                                               (i > 0) ? 1 : 0, selfq, xr, xlb);
    if (i < cNL - 1) {
      k_edge<0><<<EDGE_GRID, 256, 0, stream>>>(selfq, xr, xlb, rp_hh, src_hh,
                                               gat_att + 16 * i, gat_bias + 16 * i,
                                               nullptr, nullptr,
                                               xout, statsX + 32 * (i + 1), nullptr);
    } else {
      k_edge<1><<<EDGE_GRID, 256, 0, stream>>>(selfq, xr, xlb, rp_hh, src_hh,
                                               gat_att + 16 * i, gat_bias + 16 * i,
                                               pred_W, pred_b,
                                               nullptr, nullptr, (float*)d_out);
    }
  }
}

// Round 15
// 661.886 us; speedup vs baseline: 1.2810x; 1.0482x over previous
//
#include <hip/hip_runtime.h>
#include <hip/hip_bf16.h>
#include <cstddef>

// ---------------- problem constants ----------------
constexpr int cN_LOW  = 20000;
constexpr int cN_HIGH = 150000;
constexpr int cSEQ = 25;
constexpr int cHIN = 25;
constexpr int cHHID = 25;
constexpr int cENC = 32;
constexpr int cHIGH_IN = 7;
constexpr int cD = 16;
constexpr int cNL = 5;
constexpr int cE_L2H = 1350000;
constexpr int cE_HH = 1200000;
constexpr float cEPS = 1e-5f;
constexpr float cSLOPE = 0.2f;
constexpr float INV_NLOW  = 1.0f / (float)cN_LOW;
constexpr float INV_NHIGH = 1.0f / (float)cN_HIGH;

constexpr int cHSP = 640;     // padded hs row stride: 10 exact 64-f chunks

// scan geometry
constexpr int SC_ELEM = 1024;
constexpr int SC_NB   = (cN_HIGH + SC_ELEM - 1) / SC_ELEM;     // 147
static_assert(SC_NB <= 256, "top scan assumes <=256 partials");

// r14 sort-based CSR build (CONFIRMED −154us: dense writes fixed the 10x
// write amplification of scattered 4B stores).
constexpr int cNCB = 64;                  // coarse buckets per graph
constexpr int cCB_NODES = 2344;           // 293*8; 64*2344 = 150016 >= N_HIGH
constexpr int cSUBN = 293;                // nodes per sort block
constexpr int cNSUB = 512;                // 512*293 = 150016
constexpr int cREG1_A = 19456;            // pairs/bucket region, hh  (+5.2 sigma)
constexpr int cREG1_B = 22016;            // l2h (+6.4 sigma)
constexpr int cCAP = 6144;                // LDS stage cap (mean ~2.3-2.6K)
constexpr int cEPB = 2048;                // edges per part block
constexpr int cPT_A = (cE_HH  + cEPB - 1) / cEPB;   // 586
constexpr int cPT_B = (cE_L2H + cEPB - 1) / cEPB;   // 660

// ---------------- workspace layout (4-byte element offsets) ----------------
constexpr size_t OFF_HS   = 0;                                   // [N_LOW*640]
constexpr size_t SZ_HS    = (size_t)cN_LOW * cHSP;
constexpr size_t OFF_AGG  = 0;                                   // alias (hs dead after k_dense)
constexpr size_t OFF_ENC  = OFF_HS + SZ_HS;                      // [N_LOW*32]
constexpr size_t SZ_ENC   = (size_t)cN_LOW * cENC;
constexpr size_t OFF_XA   = OFF_ENC + SZ_ENC;
constexpr size_t OFF_XB   = OFF_XA + (size_t)cN_HIGH * cD;
constexpr size_t OFF_XL   = OFF_XB + (size_t)cN_HIGH * cD;       // selfq [N_HIGH]
constexpr size_t OFF_XR   = OFF_XL + (size_t)cN_HIGH * cD;
constexpr size_t OFF_STAT = OFF_XR + (size_t)cN_HIGH * cD;       // [256]
constexpr size_t OFF_RPH  = OFF_STAT + 256;                      // rowptr_hh [N_HIGH+4]
constexpr size_t OFF_SRH  = OFF_RPH + cN_HIGH + 4;               // src_hh [E_HH]
constexpr size_t OFF_RPL  = OFF_SRH + cE_HH;                     // rowptr_l2h [N_HIGH+4]
constexpr size_t OFF_SRL  = OFF_RPL + cN_HIGH + 4;               // src_l2h [E_L2H]
constexpr size_t OFF_CUR  = OFF_SRL + cE_L2H;                    // cursor [N_HIGH] (hh)
constexpr size_t OFF_PART = OFF_CUR + cN_HIGH;                   // partials [256] (hh)
constexpr size_t OFF_XLB  = OFF_PART + 256;                      // xl bf16 [N_HIGH*16 ushort]
// overlays in the hs region (dead until k_gru, which launches after sortcsr)
constexpr size_t OFF_CUR2 = OFF_HS;                              // cursor2 [N_HIGH]
constexpr size_t OFF_PART2= OFF_HS + cN_HIGH + 16;               // partials2 [256]
constexpr size_t OFF_SCUR = OFF_PART2 + 256 + 16;                // shardCur [128]
constexpr size_t OFF_PAIRA= OFF_SCUR + 128;                      // int2[64*cREG1_A]
constexpr size_t OFF_PAIRB= OFF_PAIRA + (size_t)2 * cNCB * cREG1_A;
static_assert(OFF_PAIRB + (size_t)2 * cNCB * cREG1_B < SZ_HS, "pair buckets fit in hs");

typedef _Float16 half_t;
typedef half_t half2_t __attribute__((ext_vector_type(2)));

__device__ __forceinline__ float fast_sigmoid(float a) {
  return __builtin_amdgcn_rcpf(1.0f + __expf(-a));
}
__device__ __forceinline__ float fast_tanh(float a) {
  float t = __expf(-2.0f * a);
  return (1.0f - t) * __builtin_amdgcn_rcpf(1.0f + t);
}
__device__ __forceinline__ unsigned int f32_to_bf16_bits(float f) {
  unsigned int u = __float_as_uint(f);
  return (u + 0x7FFFu + ((u >> 16) & 1u)) >> 16;     // RNE
}
__device__ __forceinline__ void unpack8(uint4 v, float* x) {
  const unsigned int* w = (const unsigned int*)&v;
  #pragma unroll
  for (int m = 0; m < 4; ++m) {
    x[2 * m]     = __uint_as_float(w[m] << 16);
    x[2 * m + 1] = __uint_as_float(w[m] & 0xFFFF0000u);
  }
}

// ---------------- GRU kernel v8b (FROZEN: structural floor ~89us) ---------
constexpr int GW2 = 4;                // waves per block; 2 nodes/wave -> 8/block

__global__ __launch_bounds__(256, 4)
void k_gru(const float* __restrict__ x_low,
           const float* __restrict__ Wih, const float* __restrict__ Whh,
           const float* __restrict__ bih, const float* __restrict__ bhh,
           float* __restrict__ hs) {
  __shared__ __align__(16) half_t  sx   [GW2][2][25][32];   // x, then gi2 (12.8 KB)
  __shared__ __align__(16) half2_t sgi01[GW2][2][25][32];   // (gi0,gi1)   (25.6 KB)
  __shared__ __align__(16) half_t  sh   [GW2][2][2][32];    // h dbuf      ( 1.0 KB)

  int tid  = threadIdx.x;
  int wv   = tid >> 6;
  int lane = tid & 63;
  int hf   = lane >> 5;          // node half 0/1
  int j    = lane & 31;          // 0..31; active if < 25
  bool act = j < 25;
  int nw   = blockIdx.x * GW2 + wv;       // wave's node pair index
  int n    = nw * 2 + hf;                 // this half's node

  // ---- stage x (2 nodes, 1250 contiguous floats) into LDS as half ----
  {
    const float* xb = x_low + (size_t)nw * 1250;
    for (int i = lane; i < 1250; i += 64) {
      float v = xb[i];
      int node = i / 625;
      int rem  = i - node * 625;
      int t    = rem / 25;
      int k    = rem - t * 25;
      sx[wv][node][t][k] = (half_t)v;
    }
  }
  // zero pads (k=25..31) of sx and sh so b128 reads never see garbage
  if (!act) {
    #pragma unroll
    for (int t = 0; t < cSEQ; ++t) sx[wv][hf][t][j] = (half_t)0.0f;
    sh[wv][hf][0][j] = (half_t)0.0f;
    sh[wv][hf][1][j] = (half_t)0.0f;
  } else {
    sh[wv][hf][0][j] = (half_t)0.0f;     // h0 = 0
  }

  // ---- weight regs: first Wih (prologue), then Whh (loop) ----
  half2_t w0[13], w1[13], w2[13];
  float b0 = 0.0f, b1 = 0.0f, b2 = 0.0f;
  if (act) {
    #pragma unroll
    for (int k = 0; k < 13; ++k) {
      int i0 = 2 * k, i1 = 2 * k + 1;
      float a0 = Wih[j * 25 + i0];
      float a1 = (i1 < 25) ? Wih[j * 25 + i1] : 0.0f;
      float c0 = Wih[(25 + j) * 25 + i0];
      float c1 = (i1 < 25) ? Wih[(25 + j) * 25 + i1] : 0.0f;
      float d0 = Wih[(50 + j) * 25 + i0];
      float d1 = (i1 < 25) ? Wih[(50 + j) * 25 + i1] : 0.0f;
      w0[k] = half2_t{(half_t)a0, (half_t)a1};
      w1[k] = half2_t{(half_t)c0, (half_t)c1};
      w2[k] = half2_t{(half_t)d0, (half_t)d1};
    }
    b0 = bih[j]; b1 = bih[25 + j]; b2 = bih[50 + j];
  } else {
    #pragma unroll
    for (int k = 0; k < 13; ++k) { w0[k] = half2_t{(half_t)0.0f, (half_t)0.0f};
      w1[k] = w0[k]; w2[k] = w0[k]; }
  }

  // ---- prologue: gi[t] for all t; gi0/gi1 -> sgi01, gi2 -> sx[t] (overlay)
  for (int t = 0; t < cSEQ; ++t) {
    uint4 r0 = *(const uint4*)&sx[wv][hf][t][0];
    uint4 r1 = *(const uint4*)&sx[wv][hf][t][8];
    uint4 r2 = *(const uint4*)&sx[wv][hf][t][16];
    uint4 r3 = *(const uint4*)&sx[wv][hf][t][24];
    uint4 rr[4] = {r0, r1, r2, r3};
    const half2_t* vp = (const half2_t*)rr;
    float g0 = b0, g1 = b1, g2 = b2;
    #pragma unroll
    for (int k = 0; k < 13; ++k) {
      half2_t v = vp[k];
      g0 = __builtin_amdgcn_fdot2(w0[k], v, g0, false);
      g1 = __builtin_amdgcn_fdot2(w1[k], v, g1, false);
      g2 = __builtin_amdgcn_fdot2(w2[k], v, g2, false);
    }
    if (act) {
      sgi01[wv][hf][t][j] = half2_t{(half_t)g0, (half_t)g1};
      sx[wv][hf][t][j] = (half_t)g2;      // overlay: sx[t] row dead after reads above
    }
  }

  // ---- swap weights to Whh / bhh ----
  if (act) {
    #pragma unroll
    for (int k = 0; k < 13; ++k) {
      int i0 = 2 * k, i1 = 2 * k + 1;
      float a0 = Whh[j * 25 + i0];
      float a1 = (i1 < 25) ? Whh[j * 25 + i1] : 0.0f;
      float c0 = Whh[(25 + j) * 25 + i0];
      float c1 = (i1 < 25) ? Whh[(25 + j) * 25 + i1] : 0.0f;
      float d0 = Whh[(50 + j) * 25 + i0];
      float d1 = (i1 < 25) ? Whh[(50 + j) * 25 + i1] : 0.0f;
      w0[k] = half2_t{(half_t)a0, (half_t)a1};
      w1[k] = half2_t{(half_t)c0, (half_t)c1};
      w2[k] = half2_t{(half_t)d0, (half_t)d1};
    }
    b0 = bhh[j]; b1 = bhh[25 + j]; b2 = bhh[50 + j];
  }

  float* hrow = hs + (size_t)n * cHSP;
  if (j < 15) hrow[625 + j] = 0.0f;      // zero hs pad for dense chunks

  // ---- serial loop: h-side only, 2 nodes/wave ----
  float hprev = 0.0f;
  int p = 0;
  for (int t = 0; t < cSEQ; ++t) {
    uint4 r0 = *(const uint4*)&sh[wv][hf][p][0];
    uint4 r1 = *(const uint4*)&sh[wv][hf][p][8];
    uint4 r2 = *(const uint4*)&sh[wv][hf][p][16];
    uint4 r3 = *(const uint4*)&sh[wv][hf][p][24];
    uint4 rr[4] = {r0, r1, r2, r3};
    const half2_t* vp = (const half2_t*)rr;
    float g0 = b0, g1 = b1, g2 = b2;
    #pragma unroll
    for (int k = 0; k < 13; ++k) {
      half2_t v = vp[k];
      g0 = __builtin_amdgcn_fdot2(w0[k], v, g0, false);
      g1 = __builtin_amdgcn_fdot2(w1[k], v, g1, false);
      g2 = __builtin_amdgcn_fdot2(w2[k], v, g2, false);
    }
    if (act) {
      half2_t gv = sgi01[wv][hf][t][j];
      float gi0 = (float)gv.x;
      float gi1 = (float)gv.y;
      float gi2 = (float)sx[wv][hf][t][j];   // gi2 overlay
      float r  = fast_sigmoid(gi0 + g0);
      float z  = fast_sigmoid(gi1 + g1);
      float nn = fast_tanh(gi2 + r * g2);
      float hnew = (1.0f - z) * nn + z * hprev;
      hprev = hnew;
      sh[wv][hf][p ^ 1][j] = (half_t)hnew;
      hrow[t * 25 + j] = hnew;
    }
    p ^= 1;
  }
}

// ---------------- dense 625->32 + relu + BN stats (v4) ----------------
constexpr int cDN = 32;      // nodes per block
__global__ __launch_bounds__(256)
void k_dense(const float* __restrict__ hs, const float* __restrict__ W,
             const float* __restrict__ b, float* __restrict__ enc,
             float* __restrict__ statsEnc) {
  __shared__ __align__(16) float sW2[640 * 32];        // 80 KB: [f][e2-pair]
  __shared__ __align__(16) float sH[2][cDN * 68];      // 17.4 KB
  __shared__ float sstat[2 * cENC];
  int tid = threadIdx.x;
  for (int i = tid; i < 32 * 625; i += 256) {
    int e = i / 625, f = i % 625;
    sW2[f * 32 + (e & 15) * 2 + (e >> 4)] = W[i];
  }
  for (int i = tid; i < 32 * 15; i += 256)
    sW2[(625 + (i >> 5)) * 32 + (i & 31)] = 0.0f;
  if (tid < 2 * cENC) sstat[tid] = 0.0f;

  int e2 = tid & 15;
  int ng = (tid >> 4) & 3;
  int w  = tid >> 6;
  int rA = 8 * w + 2 * ng;
  int rB = rA + 1;
  size_t nbase = (size_t)blockIdx.x * cDN;

  int srow = tid >> 4;
  int sf4  = (tid & 15) * 4;
  const float* hsb = hs + nbase * cHSP;
  {
    float4 v0 = *(const float4*)(hsb + (size_t)srow * cHSP + sf4);
    float4 v1 = *(const float4*)(hsb + (size_t)(srow + 16) * cHSP + sf4);
    *(float4*)&sH[0][srow * 68 + sf4] = v0;
    *(float4*)&sH[0][(srow + 16) * 68 + sf4] = v1;
  }
  __syncthreads();

  float a00 = 0.0f, a01 = 0.0f, a10 = 0.0f, a11 = 0.0f;
  for (int c = 0; c < 10; ++c) {
    int buf = c & 1;
    if (c + 1 < 10) {
      const float* src = hsb + (c + 1) * 64;
      float4 v0 = *(const float4*)(src + (size_t)srow * cHSP + sf4);
      float4 v1 = *(const float4*)(src + (size_t)(srow + 16) * cHSP + sf4);
      *(float4*)&sH[buf ^ 1][srow * 68 + sf4] = v0;
      *(float4*)&sH[buf ^ 1][(srow + 16) * 68 + sf4] = v1;
    }
    const float* WC = sW2 + c * 64 * 32;
    #pragma unroll
    for (int fg = 0; fg < 16; ++fg) {
      float4 hA = *(const float4*)&sH[buf][rA * 68 + fg * 4];
      float4 hB = *(const float4*)&sH[buf][rB * 68 + fg * 4];
      const float* ha = (const float*)&hA;
      const float* hb = (const float*)&hB;
      #pragma unroll
      for (int k = 0; k < 4; ++k) {
        float2 wv = *(const float2*)&WC[(fg * 4 + k) * 32 + e2 * 2];
        a00 += wv.x * ha[k]; a01 += wv.y * ha[k];
        a10 += wv.x * hb[k]; a11 += wv.y * hb[k];
      }
    }
    __syncthreads();
  }
  float blo = b[e2], bhi = b[e2 + 16];
  float v00 = fmaxf(a00 + blo, 0.0f);
  float v01 = fmaxf(a01 + bhi, 0.0f);
  float v10 = fmaxf(a10 + blo, 0.0f);
  float v11 = fmaxf(a11 + bhi, 0.0f);
  size_t nA = nbase + rA, nB = nbase + rB;
  enc[nA * cENC + e2]      = v00;
  enc[nA * cENC + e2 + 16] = v01;
  enc[nB * cENC + e2]      = v10;
  enc[nB * cENC + e2 + 16] = v11;

  float s1lo = v00 + v10, s1hi = v01 + v11;
  float s2lo = v00 * v00 + v10 * v10, s2hi = v01 * v01 + v11 * v11;
  s1lo += __shfl_xor(s1lo, 16); s1hi += __shfl_xor(s1hi, 16);
  s2lo += __shfl_xor(s2lo, 16); s2hi += __shfl_xor(s2hi, 16);
  s1lo += __shfl_xor(s1lo, 32); s1hi += __shfl_xor(s1hi, 32);
  s2lo += __shfl_xor(s2lo, 32); s2hi += __shfl_xor(s2hi, 32);
  if ((tid & 63) < 16) {
    atomicAdd(&sstat[e2], s1lo);
    atomicAdd(&sstat[e2 + 16], s1hi);
    atomicAdd(&sstat[cENC + e2], s2lo);
    atomicAdd(&sstat[cENC + e2 + 16], s2hi);
  }
  __syncthreads();
  if (tid < 2 * cENC) atomicAdd(&statsEnc[tid], sstat[tid]);
}

// ---------------- sort-based CSR build (r14, confirmed) ----------------
__global__ void k_initsc(int* __restrict__ scur) {
  int t = threadIdx.x;
  if (t < cNCB) scur[t] = t * cREG1_A;
  else if (t < 2 * cNCB) scur[t] = (t - cNCB) * cREG1_B;
}

// 64-way split with block-reserved dense runs (32 pairs = 256B per bucket)
__global__ __launch_bounds__(256)
void k_part64(const int* __restrict__ srcA, const int* __restrict__ dstA,
              const int* __restrict__ srcB, const int* __restrict__ dstB,
              int* __restrict__ scur, int2* __restrict__ pairA, int2* __restrict__ pairB) {
  __shared__ int cnt[cNCB];
  __shared__ int base_[cNCB];
  int bid = blockIdx.x;
  const int* src; const int* dst; int nE; int2* pair; int* sc;
  if (bid < cPT_A) { src = srcA; dst = dstA; nE = cE_HH; pair = pairA; sc = scur; }
  else { bid -= cPT_A; src = srcB; dst = dstB; nE = cE_L2H; pair = pairB; sc = scur + cNCB; }
  int tid = threadIdx.x;
  for (int i = tid; i < cNCB; i += 256) cnt[i] = 0;
  __syncthreads();
  int e0 = bid * cEPB;
  int myd[8], mys[8], myb[8];
  #pragma unroll
  for (int k = 0; k < 8; ++k) {
    int e = e0 + k * 256 + tid;
    if (e < nE) {
      int d = __builtin_nontemporal_load(dst + e);
      int s = __builtin_nontemporal_load(src + e);
      myd[k] = d; mys[k] = s;
      int b = d / cCB_NODES;
      myb[k] = b;
      atomicAdd(&cnt[b], 1);
    } else myb[k] = -1;
  }
  __syncthreads();
  for (int i = tid; i < cNCB; i += 256) base_[i] = atomicAdd(&sc[i], cnt[i]);
  __syncthreads();
  for (int i = tid; i < cNCB; i += 256) cnt[i] = 0;    // reuse as rank cursors
  __syncthreads();
  #pragma unroll
  for (int k = 0; k < 8; ++k) {
    if (myb[k] >= 0) {
      int r = atomicAdd(&cnt[myb[k]], 1);
      pair[base_[myb[k]] + r] = make_int2(mys[k], myd[k]);
    }
  }
}

// per-293-node block: LDS hist over its coarse bucket, dense deg write
__global__ __launch_bounds__(256)
void k_subhist(const int2* __restrict__ pairA, int* __restrict__ degA,
               const int2* __restrict__ pairB, int* __restrict__ degB,
               const int* __restrict__ scur) {
  __shared__ int h[cSUBN];
  int bid = blockIdx.x;
  const int2* pair; int* deg; const int* sc; int reg;
  if (bid < cNSUB) { pair = pairA; deg = degA; sc = scur; reg = cREG1_A; }
  else { bid -= cNSUB; pair = pairB; deg = degB; sc = scur + cNCB; reg = cREG1_B; }
  int cb = bid & 63;
  int s  = bid >> 6;
  int lo = cb * cCB_NODES + s * cSUBN;
  int hi = min(lo + cSUBN, cN_HIGH);
  if (lo >= cN_HIGH) return;
  int tid = threadIdx.x;
  for (int i = tid; i < cSUBN; i += 256) h[i] = 0;
  __syncthreads();
  int fill = sc[cb] - cb * reg;
  const int2* bk = pair + (size_t)cb * reg;
  for (int i = tid; i < fill; i += 256) {
    int d = bk[i].y;
    if (d >= lo && d < hi) atomicAdd(&h[d - lo], 1);
  }
  __syncthreads();
  for (int i = tid; i < hi - lo; i += 256) deg[lo + i] = h[i];
}

// per-293-node block: LDS rank + LDS stage, single contiguous out write
__global__ __launch_bounds__(256)
void k_sortcsr(const int2* __restrict__ pairA, const int* __restrict__ rpA,
               int* __restrict__ curA, int* __restrict__ outA,
               const int2* __restrict__ pairB, const int* __restrict__ rpB,
               int* __restrict__ curB, int* __restrict__ outB,
               const int* __restrict__ scur) {
  __shared__ int rp[cSUBN + 1];
  __shared__ int rc[cSUBN];
  __shared__ int stage[cCAP];
  int bid = blockIdx.x;
  const int2* pair; const int* rowptr; int* cur; int* out; const int* sc; int reg;
  if (bid < cNSUB) { pair = pairA; rowptr = rpA; cur = curA; out = outA; sc = scur; reg = cREG1_A; }
  else { bid -= cNSUB; pair = pairB; rowptr = rpB; cur = curB; out = outB; sc = scur + cNCB; reg = cREG1_B; }
  int cb = bid & 63;
  int s  = bid >> 6;
  int lo = cb * cCB_NODES + s * cSUBN;
  int hi = min(lo + cSUBN, cN_HIGH);
  if (lo >= cN_HIGH) return;
  int nn = hi - lo;
  int tid = threadIdx.x;
  for (int i = tid; i <= nn; i += 256) rp[i] = rowptr[lo + i];
  for (int i = tid; i < nn; i += 256) rc[i] = 0;
  __syncthreads();
  int gbase = rp[0];
  int count = rp[nn] - gbase;
  int fill = sc[cb] - cb * reg;
  const int2* bk = pair + (size_t)cb * reg;
  if (count <= cCAP) {
    for (int i = tid; i < fill; i += 256) {
      int2 p = bk[i];
      int d = p.y;
      if (d >= lo && d < hi) {
        int j = d - lo;
        int r = atomicAdd(&rc[j], 1);
        stage[rp[j] - gbase + r] = p.x;
      }
    }
    __syncthreads();
    for (int i = tid; i < count; i += 256) out[gbase + i] = stage[i];
  } else {
    // overflow fallback (never expected: cap is +79 sigma); cursor = rowptr copy
    for (int i = tid; i < fill; i += 256) {
      int2 p = bk[i];
      int d = p.y;
      if (d >= lo && d < hi) {
        int pos = atomicAdd(&cur[d], 1);
        out[pos] = p.x;
      }
    }
  }
}

__global__ void k_scan_local2(const int* __restrict__ degA, int* __restrict__ outA,
                              int* __restrict__ partA,
                              const int* __restrict__ degB, int* __restrict__ outB,
                              int* __restrict__ partB) {
  int bid = blockIdx.x;
  const int* deg; int* out; int* partial;
  if (bid < SC_NB) { deg = degA; out = outA; partial = partA; }
  else { bid -= SC_NB; deg = degB; out = outB; partial = partB; }
  const int n = cN_HIGH;
  int tid = threadIdx.x;
  int base = bid * SC_ELEM + tid * 4;
  int4 v = make_int4(0, 0, 0, 0);
  if (base + 3 < n) v = *(const int4*)(deg + base);
  else { int* pv = (int*)&v; for (int k = 0; k < 4; ++k) if (base + k < n) pv[k] = deg[base + k]; }
  int tsum = v.x + v.y + v.z + v.w;
  int lane = tid & 63;
  int inc = tsum;
  #pragma unroll
  for (int o = 1; o < 64; o <<= 1) { int t = __shfl_up(inc, o); if (lane >= o) inc += t; }
  __shared__ int wtot[4];
  if (lane == 63) wtot[tid >> 6] = inc;
  __syncthreads();
  int w = tid >> 6, wbase = 0;
  #pragma unroll
  for (int k = 0; k < 3; ++k) if (k < w) wbase += wtot[k];
  int ebase = wbase + inc - tsum;
  int4 o4;
  o4.x = ebase; o4.y = ebase + v.x; o4.z = o4.y + v.y; o4.w = o4.z + v.z;
  if (base + 3 < n) *(int4*)(out + base) = o4;
  else { int* po = (int*)&o4; for (int k = 0; k < 4; ++k) if (base + k < n) out[base + k] = po[k]; }
  if (tid == 255) partial[bid] = wbase + inc;
}

__global__ void k_scan_top2(int* __restrict__ partA, int* __restrict__ totalA,
                            int* __restrict__ partB, int* __restrict__ totalB) {
  int* partial = (blockIdx.x == 0) ? partA : partB;
  int* total_out = (blockIdx.x == 0) ? totalA : totalB;
  const int nb = SC_NB;
  __shared__ int sd[256];
  int tid = threadIdx.x;
  int v = (tid < nb) ? partial[tid] : 0;
  sd[tid] = v;
  __syncthreads();
  for (int off = 1; off < 256; off <<= 1) {
    int t = (tid >= off) ? sd[tid - off] : 0;
    __syncthreads();
    sd[tid] += t;
    __syncthreads();
  }
  if (tid < nb) partial[tid] = sd[tid] - v;
  if (tid == 255) *total_out = sd[255];
}

__global__ void k_scan_add2(int* __restrict__ rpA, const int* __restrict__ partA,
                            int* __restrict__ curA,
                            int* __restrict__ rpB, const int* __restrict__ partB,
                            int* __restrict__ curB) {
  int bid = blockIdx.x;
  int* rowptr; const int* partial; int* cursor;
  if (bid < SC_NB) { rowptr = rpA; partial = partA; cursor = curA; }
  else { bid -= SC_NB; rowptr = rpB; partial = partB; cursor = curB; }
  const int n = cN_HIGH;
  int base = bid * SC_ELEM + threadIdx.x * 4;
  int add = partial[bid];
  if (base + 3 < n) {
    int4 v = *(int4*)(rowptr + base);
    v.x += add; v.y += add; v.z += add; v.w += add;
    *(int4*)(rowptr + base) = v;
    *(int4*)(cursor + base) = v;
  } else {
    for (int k = 0; k < 4; ++k)
      if (base + k < n) { int t = rowptr[base + k] + add; rowptr[base + k] = t; cursor[base + k] = t; }
  }
}

// ---------------- l2h gather via CSR (2-way unrolled) ----------------
__global__ void k_gather_csr(const float* __restrict__ enc, const int* __restrict__ rowptr,
                             const int* __restrict__ srcs, const float* __restrict__ statsEnc,
                             const float* __restrict__ g, const float* __restrict__ bb,
                             float* __restrict__ agg) {
  __shared__ float ssc[cENC], ssh[cENC];
  int tid = threadIdx.x;
  if (tid < cENC) {
    float m = statsEnc[tid] * INV_NLOW;
    float var = statsEnc[cENC + tid] * INV_NLOW - m * m;
    float sc = g[tid] * rsqrtf(var + cEPS);
    ssc[tid] = sc;
    ssh[tid] = bb[tid] - m * sc;
  }
  __syncthreads();
  int c = tid & 31;
  int n = blockIdx.x * 8 + (tid >> 5);
  int lo = rowptr[n], hi = rowptr[n + 1];
  float sum = 0.0f;
  int i = lo;
  for (; i + 1 < hi; i += 2) {
    int s0 = srcs[i], s1 = srcs[i + 1];
    sum += enc[(size_t)s0 * cENC + c] + enc[(size_t)s1 * cENC + c];
  }
  if (i < hi) sum += enc[(size_t)srcs[i] * cENC + c];
  float deg = (float)(hi - lo);
  agg[(size_t)n * cENC + c] = (ssc[c] * sum + deg * ssh[c]) / fmaxf(deg, 1.0f);
}

// ---------------- down-projection + BN0 stats ----------------
__global__ void k_down(const float* __restrict__ agg,
                       const float* __restrict__ z_std, const float* __restrict__ land,
                       const float* __restrict__ Wrel, const float* __restrict__ brel,
                       const float* __restrict__ Wroot,
                       float* __restrict__ x0, float* __restrict__ stats) {
  __shared__ float sstat[2 * cD];
  __shared__ float sWrel[cD * cENC], sWroot[cD * cHIGH_IN], sbrel[cD];
  int tid = threadIdx.x;
  if (tid < 2 * cD) sstat[tid] = 0.0f;
  for (int i = tid; i < cD * cENC; i += 256) sWrel[i] = Wrel[i];
  if (tid < cD * cHIGH_IN) sWroot[tid] = Wroot[tid];
  if (tid < cD) sbrel[tid] = brel[tid];
  __syncthreads();

  int n = blockIdx.x * 256 + tid;
  bool valid = n < cN_HIGH;
  float a[cENC], zz[cHIGH_IN];
  if (valid) {
    const float4* ar4 = (const float4*)(agg + (size_t)n * cENC);
    #pragma unroll
    for (int k = 0; k < cENC / 4; ++k) {
      float4 t4 = ar4[k];
      a[4*k] = t4.x; a[4*k+1] = t4.y; a[4*k+2] = t4.z; a[4*k+3] = t4.w;
    }
    #pragma unroll
    for (int k = 0; k < 6; ++k) zz[k] = z_std[(size_t)n * 6 + k];
    zz[6] = land[n];
  } else {
    #pragma unroll
    for (int k = 0; k < cENC; ++k) a[k] = 0.0f;
    #pragma unroll
    for (int k = 0; k < cHIGH_IN; ++k) zz[k] = 0.0f;
  }
  int lane = tid & 63;
  #pragma unroll
  for (int d = 0; d < cD; ++d) {
    float acc = sbrel[d];
    #pragma unroll
    for (int k = 0; k < cENC; ++k) acc += a[k] * sWrel[d * cENC + k];
    #pragma unroll
    for (int k = 0; k < cHIGH_IN; ++k) acc += zz[k] * sWroot[d * cHIGH_IN + k];
    if (valid) x0[(size_t)n * cD + d] = acc;
    float v = valid ? acc : 0.0f;
    float s1 = v, s2 = v * v;
    #pragma unroll
    for (int o = 32; o > 0; o >>= 1) { s1 += __shfl_down(s1, o); s2 += __shfl_down(s2, o); }
    if (lane == 0) { atomicAdd(&sstat[d], s1); atomicAdd(&sstat[cD + d], s2); }
  }
  __syncthreads();
  if (tid < 2 * cD) atomicAdd(&stats[tid], sstat[tid]);
}

// ---------------- per-layer BN stats over xout (r15) ----------------
// Replaces the in-k_edge stats tail: 1172 blocks x 32 same-address global
// atomics (37.5K serialized RMWs) -> 128 blocks streaming xout densely,
// wave-shfl reduce, 4096 atomics total.
__global__ __launch_bounds__(256)
void k_stats(const float* __restrict__ x, float* __restrict__ stats) {
  __shared__ float sacc[2][cD];
  int tid = threadIdx.x;
  if (tid < 2 * cD) sacc[tid >> 4][tid & 15] = 0.0f;
  __syncthreads();
  float s1[4] = {0, 0, 0, 0}, s2[4] = {0, 0, 0, 0};
  const float4* x4 = (const float4*)x;
  const int total4 = cN_HIGH * 4;                 // 600000 float4s
  // stride 128*256 = 32768 ≡ 0 mod 4 -> phase = tid&3 is loop-invariant
  for (int i = blockIdx.x * 256 + tid; i < total4; i += 128 * 256) {
    float4 v = x4[i];
    s1[0] += v.x; s1[1] += v.y; s1[2] += v.z; s1[3] += v.w;
    s2[0] += v.x * v.x; s2[1] += v.y * v.y; s2[2] += v.z * v.z; s2[3] += v.w * v.w;
  }
  // lanes with equal (lane&3) hold the same 4-channel group
  #pragma unroll
  for (int o = 4; o < 64; o <<= 1) {
    #pragma unroll
    for (int k = 0; k < 4; ++k) {
      s1[k] += __shfl_xor(s1[k], o);
      s2[k] += __shfl_xor(s2[k], o);
    }
  }
  if ((tid & 63) < 4) {
    int d = (tid & 3) * 4;
    #pragma unroll
    for (int k = 0; k < 4; ++k) {
      atomicAdd(&sacc[0][d + k], s1[k]);
      atomicAdd(&sacc[1][d + k], s2[k]);
    }
  }
  __syncthreads();
  if (tid < cD) atomicAdd(&stats[tid], sacc[0][tid]);
  else if (tid < 2 * cD) atomicAdd(&stats[tid], sacc[1][tid & 15]);
}

// ---------------- GAT node transform (emits xr, xlb bf16, self-logit) -----
__global__ void k_transform(const float* __restrict__ xin, const float* __restrict__ stats,
                            const float* __restrict__ g, const float* __restrict__ b,
                            const float* __restrict__ Wl, const float* __restrict__ bl,
                            const float* __restrict__ Wr, const float* __restrict__ br,
                            const float* __restrict__ att,
                            int applyRelu,
                            float* __restrict__ selfq, float* __restrict__ xr,
                            unsigned short* __restrict__ xlb) {
  __shared__ float ssc[cD], ssh[cD], sWl[cD * cD], sWr[cD * cD], sbl[cD], sbr[cD], satt[cD];
  int tid = threadIdx.x;
  if (tid < cD) {
    float m = stats[tid] * INV_NHIGH;
    float v = stats[cD + tid] * INV_NHIGH - m * m;
    float sc = g[tid] * rsqrtf(v + cEPS);
    ssc[tid] = sc;
    ssh[tid] = b[tid] - m * sc;
    sbl[tid] = bl[tid];
    sbr[tid] = br[tid];
    satt[tid] = att[tid];
  }
  if (tid < cD * cD) { sWl[tid] = Wl[tid]; sWr[tid] = Wr[tid]; }
  __syncthreads();

  int n = blockIdx.x * 256 + tid;
  if (n >= cN_HIGH) return;
  float act[cD];
  const float* xp = xin + (size_t)n * cD;
  #pragma unroll
  for (int d = 0; d < cD; ++d) {
    float v = xp[d] * ssc[d] + ssh[d];
    if (applyRelu) v = fmaxf(v, 0.0f);
    act[d] = v;
  }
  float alv[cD], arv[cD];
  float* xrp = xr + (size_t)n * cD;
  #pragma unroll
  for (int d = 0; d < cD; ++d) {
    float al = sbl[d], ar = sbr[d];
    #pragma unroll
    for (int k = 0; k < cD; ++k) { al += act[k] * sWl[d * cD + k]; ar += act[k] * sWr[d * cD + k]; }
    alv[d] = al;
    arv[d] = ar;
    xrp[d] = ar;
  }
  // self-loop attention logit
  float qq = 0.0f;
  #pragma unroll
  for (int d = 0; d < cD; ++d) {
    float u = alv[d] + arv[d];
    u = fmaxf(u, cSLOPE * u);
    qq += u * satt[d];
  }
  selfq[n] = qq;

  uint4 w0, w1;
  unsigned int* pw = (unsigned int*)&w0;
  #pragma unroll
  for (int k = 0; k < 4; ++k)
    pw[k] = f32_to_bf16_bits(alv[2 * k]) | (f32_to_bf16_bits(alv[2 * k + 1]) << 16);
  unsigned int* pw1 = (unsigned int*)&w1;
  #pragma unroll
  for (int k = 0; k < 4; ++k)
    pw1[k] = f32_to_bf16_bits(alv[8 + 2 * k]) | (f32_to_bf16_bits(alv[8 + 2 * k + 1]) << 16);
  uint4* dst = (uint4*)(xlb + (size_t)n * cD);
  dst[0] = w0;
  dst[1] = w1;
}

// ---------------- fused GAT edge pass v7: stats tail removed (r15) --------
template<int FINAL>
__global__ __launch_bounds__(256)
void k_edge(const float* __restrict__ selfq, const float* __restrict__ xr,
            const unsigned short* __restrict__ xlb,
            const int* __restrict__ rowptr, const int* __restrict__ srcs,
            const float* __restrict__ att, const float* __restrict__ bias,
            const float* __restrict__ pW, const float* __restrict__ pb,
            float* __restrict__ xout, float* __restrict__ out) {
  int tid = threadIdx.x;
  int half = tid & 1;
  int n = (blockIdx.x * 256 + tid) >> 1;
  bool valid = n < cN_HIGH;
  int base = half * 8;

  float av[8];
  #pragma unroll
  for (int k = 0; k < 8; ++k) av[k] = att[base + k];

  const uint4* xl4 = (const uint4*)xlb;
  float xrv[8], num[8];
  float denom = 1.0f;
  int lo = 0, hi = 0;
  if (valid) {
    #pragma unroll
    for (int k = 0; k < 2; ++k) {
      float4 t = *(const float4*)(xr + (size_t)n * cD + base + 4 * k);
      xrv[4*k] = t.x; xrv[4*k+1] = t.y; xrv[4*k+2] = t.z; xrv[4*k+3] = t.w;
    }
    // self contribution: own bf16 row + precomputed logit
    uint4 vs = xl4[(size_t)n * 2 + half];
    float xsv[8];
    unpack8(vs, xsv);
    float e = __expf(selfq[n]);
    denom = e;
    #pragma unroll
    for (int k = 0; k < 8; ++k) num[k] = e * xsv[k];
    lo = rowptr[n]; hi = rowptr[n + 1];
  } else {
    #pragma unroll
    for (int k = 0; k < 8; ++k) { num[k] = 0.0f; xrv[k] = 0.0f; }
  }

  int i = lo;
  for (; i + 3 < hi; i += 4) {
    int s0 = srcs[i], s1 = srcs[i + 1], s2 = srcs[i + 2], s3 = srcs[i + 3];
    uint4 v0 = xl4[(size_t)s0 * 2 + half];
    uint4 v1 = xl4[(size_t)s1 * 2 + half];
    uint4 v2 = xl4[(size_t)s2 * 2 + half];
    uint4 v3 = xl4[(size_t)s3 * 2 + half];
    float x0[8], x1[8], x2[8], x3[8];
    unpack8(v0, x0);
    unpack8(v1, x1);
    unpack8(v2, x2);
    unpack8(v3, x3);
    float q0 = 0.0f, q1 = 0.0f, q2 = 0.0f, q3 = 0.0f;
    #pragma unroll
    for (int k = 0; k < 8; ++k) {
      float u0 = x0[k] + xrv[k]; u0 = fmaxf(u0, cSLOPE * u0);
      float u1 = x1[k] + xrv[k]; u1 = fmaxf(u1, cSLOPE * u1);
      float u2 = x2[k] + xrv[k]; u2 = fmaxf(u2, cSLOPE * u2);
      float u3 = x3[k] + xrv[k]; u3 = fmaxf(u3, cSLOPE * u3);
      q0 += u0 * av[k]; q1 += u1 * av[k]; q2 += u2 * av[k]; q3 += u3 * av[k];
    }
    q0 += __shfl_xor(q0, 1);
    q1 += __shfl_xor(q1, 1);
    q2 += __shfl_xor(q2, 1);
    q3 += __shfl_xor(q3, 1);
    float e0 = __expf(q0), e1 = __expf(q1), e2 = __expf(q2), e3 = __expf(q3);
    denom += (e0 + e1) + (e2 + e3);
    #pragma unroll
    for (int k = 0; k < 8; ++k)
      num[k] += (e0 * x0[k] + e1 * x1[k]) + (e2 * x2[k] + e3 * x3[k]);
  }
  for (; i + 1 < hi; i += 2) {
    int s0 = srcs[i], s1 = srcs[i + 1];
    uint4 v0 = xl4[(size_t)s0 * 2 + half];
    uint4 v1 = xl4[(size_t)s1 * 2 + half];
    float x0[8], x1[8];
    unpack8(v0, x0);
    unpack8(v1, x1);
    float q0 = 0.0f, q1 = 0.0f;
    #pragma unroll
    for (int k = 0; k < 8; ++k) {
      float u0 = x0[k] + xrv[k]; u0 = fmaxf(u0, cSLOPE * u0);
      float u1 = x1[k] + xrv[k]; u1 = fmaxf(u1, cSLOPE * u1);
      q0 += u0 * av[k]; q1 += u1 * av[k];
    }
    q0 += __shfl_xor(q0, 1);
    q1 += __shfl_xor(q1, 1);
    float e0 = __expf(q0), e1 = __expf(q1);
    denom += e0 + e1;
    #pragma unroll
    for (int k = 0; k < 8; ++k) num[k] += e0 * x0[k] + e1 * x1[k];
  }
  if (i < hi) {
    int s = srcs[i];
    uint4 v = xl4[(size_t)s * 2 + half];
    float x[8];
    unpack8(v, x);
    float qq = 0.0f;
    #pragma unroll
    for (int k = 0; k < 8; ++k) {
      float u = x[k] + xrv[k]; u = fmaxf(u, cSLOPE * u);
      qq += u * av[k];
    }
    qq += __shfl_xor(qq, 1);
    float e = __expf(qq);
    denom += e;
    #pragma unroll
    for (int k = 0; k < 8; ++k) num[k] += e * x[k];
  }

  if (!valid) return;
  float cnt = (float)(hi - lo + 1);
  float inv = __builtin_amdgcn_rcpf(denom * cnt);
  float res[8];
  #pragma unroll
  for (int k = 0; k < 8; ++k)
    res[k] = num[k] * inv + bias[base + k];

  if (FINAL) {
    float t = 0.0f;
    #pragma unroll
    for (int k = 0; k < 8; ++k) t += fmaxf(res[k], 0.0f) * pW[base + k];
    t += __shfl_xor(t, 1);
    if (half == 0) out[n] = t + pb[0];
  } else {
    float4* op = (float4*)(xout + (size_t)n * cD + base);
    op[0] = make_float4(res[0], res[1], res[2], res[3]);
    op[1] = make_float4(res[4], res[5], res[6], res[7]);
  }
}

// ---------------- launch ----------------
extern "C" void kernel_launch(void* const* d_in, const int* in_sizes, int n_in,
                              void* d_out, int out_size, void* d_ws, size_t ws_size,
                              hipStream_t stream) {
  const float* x_low    = (const float*)d_in[0];
  const float* z_std    = (const float*)d_in[1];
  const float* land     = (const float*)d_in[2];
  const int*   l2h_src  = (const int*)d_in[3];
  const int*   l2h_dst  = (const int*)d_in[4];
  const int*   hh_src   = (const int*)d_in[5];
  const int*   hh_dst   = (const int*)d_in[6];
  const float* gWih     = (const float*)d_in[7];
  const float* gWhh     = (const float*)d_in[8];
  const float* gbih     = (const float*)d_in[9];
  const float* gbhh     = (const float*)d_in[10];
  const float* dW       = (const float*)d_in[11];
  const float* db       = (const float*)d_in[12];
  const float* bn_enc_g = (const float*)d_in[13];
  const float* bn_enc_b = (const float*)d_in[14];
  const float* Wrel     = (const float*)d_in[15];
  const float* brel     = (const float*)d_in[16];
  const float* Wroot    = (const float*)d_in[17];
  const float* gat_Wl   = (const float*)d_in[18];
  const float* gat_bl   = (const float*)d_in[19];
  const float* gat_Wr   = (const float*)d_in[20];
  const float* gat_br   = (const float*)d_in[21];
  const float* gat_att  = (const float*)d_in[22];
  const float* gat_bias = (const float*)d_in[23];
  const float* bn_g     = (const float*)d_in[24];
  const float* bn_b     = (const float*)d_in[25];
  const float* pred_W   = (const float*)d_in[26];
  const float* pred_b   = (const float*)d_in[27];

  float* ws = (float*)d_ws;
  float* hs   = ws + OFF_HS;
  float* agg  = ws + OFF_AGG;
  float* enc  = ws + OFF_ENC;
  float* xA   = ws + OFF_XA;
  float* xB   = ws + OFF_XB;
  float* selfq= ws + OFF_XL;          // retired xl f32 slot -> self logits
  float* xr   = ws + OFF_XR;
  float* statsEnc = ws + OFF_STAT;
  float* statsX   = ws + OFF_STAT + 64;
  int* rp_hh  = (int*)(ws + OFF_RPH);
  int* src_hh = (int*)(ws + OFF_SRH);
  int* rp_l2h = (int*)(ws + OFF_RPL);
  int* src_l2h= (int*)(ws + OFF_SRL);
  int* cursor = (int*)(ws + OFF_CUR);
  int* part   = (int*)(ws + OFF_PART);
  unsigned short* xlb = (unsigned short*)(ws + OFF_XLB);
  // overlays in hs region (dead until k_gru)
  int*  cursor2 = (int*)(ws + OFF_CUR2);
  int*  part2   = (int*)(ws + OFF_PART2);
  int*  scur    = (int*)(ws + OFF_SCUR);
  int2* pairA   = (int2*)(ws + OFF_PAIRA);
  int2* pairB   = (int2*)(ws + OFF_PAIRB);

  hipMemsetAsync(statsEnc, 0, 256 * sizeof(float), stream);
  const int NODE_GRID = (cN_HIGH + 255) / 256;

  // --- sort-based CSR build (no cursor memsets: subhist writes all deg) ---
  k_initsc<<<1, 128, 0, stream>>>(scur);
  k_part64<<<cPT_A + cPT_B, 256, 0, stream>>>(hh_src, hh_dst, l2h_src, l2h_dst,
                                              scur, pairA, pairB);
  k_subhist<<<2 * cNSUB, 256, 0, stream>>>(pairA, cursor, pairB, cursor2, scur);
  k_scan_local2<<<2 * SC_NB, 256, 0, stream>>>(cursor, rp_hh, part,
                                               cursor2, rp_l2h, part2);
  k_scan_top2<<<2, 256, 0, stream>>>(part, rp_hh + cN_HIGH,
                                     part2, rp_l2h + cN_HIGH);
  k_scan_add2<<<2 * SC_NB, 256, 0, stream>>>(rp_hh, part, cursor,
                                             rp_l2h, part2, cursor2);
  k_sortcsr<<<2 * cNSUB, 256, 0, stream>>>(pairA, rp_hh, cursor, src_hh,
                                           pairB, rp_l2h, cursor2, src_l2h, scur);

  // --- encoder ---
  k_gru<<<cN_LOW / (2 * GW2), 256, 0, stream>>>(x_low, gWih, gWhh, gbih, gbhh, hs);
  k_dense<<<cN_LOW / cDN, 256, 0, stream>>>(hs, dW, db, enc, statsEnc);
  k_gather_csr<<<cN_HIGH / 8, 256, 0, stream>>>(enc, rp_l2h, src_l2h, statsEnc,
                                                bn_enc_g, bn_enc_b, agg);
  k_down<<<NODE_GRID, 256, 0, stream>>>(agg, z_std, land, Wrel, brel, Wroot, xA, statsX);

  const int EDGE_GRID = (2 * cN_HIGH + 255) / 256;
  // --- 5 GATv2 layers ---
  for (int i = 0; i < cNL; ++i) {
    float* xin  = (i & 1) ? xB : xA;
    float* xout = (i & 1) ? xA : xB;
    k_transform<<<NODE_GRID, 256, 0, stream>>>(xin, statsX + 32 * i,
                                               bn_g + 16 * i, bn_b + 16 * i,
                                               gat_Wl + 256 * i, gat_bl + 16 * i,
                                               gat_Wr + 256 * i, gat_br + 16 * i,
                                               gat_att + 16 * i,
                                               (i > 0) ? 1 : 0, selfq, xr, xlb);
    if (i < cNL - 1) {
      k_edge<0><<<EDGE_GRID, 256, 0, stream>>>(selfq, xr, xlb, rp_hh, src_hh,
                                               gat_att + 16 * i, gat_bias + 16 * i,
                                               nullptr, nullptr,
                                               xout, nullptr);
      k_stats<<<128, 256, 0, stream>>>(xout, statsX + 32 * (i + 1));
    } else {
      k_edge<1><<<EDGE_GRID, 256, 0, stream>>>(selfq, xr, xlb, rp_hh, src_hh,
                                               gat_att + 16 * i, gat_bias + 16 * i,
                                               pred_W, pred_b,
                                               nullptr, (float*)d_out);
    }
  }
}